// Round 1
// baseline (2000.190 us; speedup 1.0000x reference)
//
#include <hip/hip_runtime.h>
#include <hip/hip_bf16.h>

namespace {

constexpr int B  = 2;
constexpr int C  = 64;
constexpr int CQ = 8;
constexpr int H  = 270;
constexpr int W  = 480;
constexpr int HW = H * W;
constexpr float INVH2 = 2.0f / (270.0f * 270.0f);  // dw_h = exp(-d^2 * INVH2)
constexpr float INVW2 = 2.0f / (480.0f * 480.0f);

__device__ __forceinline__ float bits2f(unsigned short u) {
  union { unsigned int i; float f; } cv;
  cv.i = ((unsigned int)u) << 16;
  return cv.f;
}

__device__ __forceinline__ unsigned short f2bf(float f) {
  union { __hip_bfloat16 b; unsigned short u; } cv;
  cv.b = __float2bfloat16(f);
  return cv.u;
}

// ---------------------------------------------------------------------------
// K1: q/k/v 1x1 projections. One thread per pixel. Writes q,k (f32, normal),
// q_t,k_t (f32, [b][w][h][8]), v (bf16 normal), v_t (bf16, [b][w][g][c]).
// All weight reads are LDS broadcasts (same address across lanes).
// ---------------------------------------------------------------------------
__global__ __launch_bounds__(256)
void k_qkv(const float* __restrict__ x,
           const float* __restrict__ Wq, const float* __restrict__ bq,
           const float* __restrict__ Wk, const float* __restrict__ bk,
           const float* __restrict__ Wv, const float* __restrict__ bv,
           float* __restrict__ q, float* __restrict__ k,
           float* __restrict__ qt, float* __restrict__ kt,
           unsigned short* __restrict__ v, unsigned short* __restrict__ vt) {
  __shared__ __align__(16) float wql[CQ * C];
  __shared__ __align__(16) float wkl[CQ * C];
  __shared__ __align__(16) float wvl[C * C];
  __shared__ float bql[CQ], bkl[CQ], bvl[C];
  const int tid = threadIdx.x;
  for (int i = tid; i < CQ * C; i += 256) { wql[i] = Wq[i]; wkl[i] = Wk[i]; }
  for (int i = tid; i < C * C; i += 256) wvl[i] = Wv[i];
  if (tid < CQ) { bql[tid] = bq[tid]; bkl[tid] = bk[tid]; }
  if (tid < C) bvl[tid] = bv[tid];
  __syncthreads();
  const int pix = blockIdx.x * 256 + tid;
  if (pix >= B * HW) return;
  const int b = pix / HW;
  const int r = pix - b * HW;
  const int h = r / W;
  const int w = r - h * W;

  float qa[CQ], ka[CQ], va[C];
#pragma unroll
  for (int o = 0; o < CQ; ++o) { qa[o] = bql[o]; ka[o] = bkl[o]; }
#pragma unroll
  for (int o = 0; o < C; ++o) va[o] = bvl[o];

  const float* xp = x + (size_t)b * C * HW + r;
  for (int c = 0; c < C; c += 4) {
    const float x0 = xp[(size_t)(c + 0) * HW];
    const float x1 = xp[(size_t)(c + 1) * HW];
    const float x2 = xp[(size_t)(c + 2) * HW];
    const float x3 = xp[(size_t)(c + 3) * HW];
#pragma unroll
    for (int o = 0; o < CQ; ++o) {
      const float4 a = *(const float4*)(wql + o * C + c);
      qa[o] = fmaf(a.w, x3, fmaf(a.z, x2, fmaf(a.y, x1, fmaf(a.x, x0, qa[o]))));
      const float4 bb = *(const float4*)(wkl + o * C + c);
      ka[o] = fmaf(bb.w, x3, fmaf(bb.z, x2, fmaf(bb.y, x1, fmaf(bb.x, x0, ka[o]))));
    }
#pragma unroll
    for (int o = 0; o < C; ++o) {
      const float4 cc = *(const float4*)(wvl + o * C + c);
      va[o] = fmaf(cc.w, x3, fmaf(cc.z, x2, fmaf(cc.y, x1, fmaf(cc.x, x0, va[o]))));
    }
  }

  float* qp = q + (size_t)b * CQ * HW + r;
  float* kp = k + (size_t)b * CQ * HW + r;
#pragma unroll
  for (int o = 0; o < CQ; ++o) { qp[(size_t)o * HW] = qa[o]; kp[(size_t)o * HW] = ka[o]; }
  unsigned short* vp = v + (size_t)b * C * HW + r;
#pragma unroll
  for (int o = 0; o < C; ++o) vp[(size_t)o * HW] = f2bf(va[o]);

  float4* qtp = (float4*)(qt + (((size_t)b * W + w) * H + h) * CQ);
  qtp[0] = make_float4(qa[0], qa[1], qa[2], qa[3]);
  qtp[1] = make_float4(qa[4], qa[5], qa[6], qa[7]);
  float4* ktp = (float4*)(kt + (((size_t)b * W + w) * H + h) * CQ);
  ktp[0] = make_float4(ka[0], ka[1], ka[2], ka[3]);
  ktp[1] = make_float4(ka[4], ka[5], ka[6], ka[7]);
  unsigned short* vtp = vt + (((size_t)b * W + w) * H + h) * C;
#pragma unroll
  for (int j = 0; j < 16; ++j) {
    ushort4 u;
    u.x = f2bf(va[4 * j + 0]);
    u.y = f2bf(va[4 * j + 1]);
    u.z = f2bf(va[4 * j + 2]);
    u.w = f2bf(va[4 * j + 3]);
    *(ushort4*)(vtp + 4 * j) = u;
  }
}

// ---------------------------------------------------------------------------
// K2a: per-(b,w) column softmax stats over g (diag h==g masked out).
// mh/sh layout [b][w][h].
// ---------------------------------------------------------------------------
__global__ __launch_bounds__(256)
void k_colstats(const float* __restrict__ qt, const float* __restrict__ kt,
                float* __restrict__ mh, float* __restrict__ sh) {
  const int w = blockIdx.x, b = blockIdx.y;
  __shared__ float ql[H * 9];
  __shared__ __align__(16) float kl[H * CQ];
  __shared__ float mrgm[4][64], mrgs[4][64];
  const int tid = threadIdx.x;
  const float* qcol = qt + (((size_t)b * W + w) * H) * CQ;
  const float* kcol = kt + (((size_t)b * W + w) * H) * CQ;
  for (int i = tid; i < H * CQ; i += 256) {
    ql[(i >> 3) * 9 + (i & 7)] = qcol[i];
    kl[i] = kcol[i];
  }
  __syncthreads();
  const int s = tid >> 6, hs = tid & 63;
  const int gb = s * 68, ge = min(H, gb + 68);
  for (int it = 0; it < 5; ++it) {
    const int h = hs + it * 64;
    float m = -INFINITY, ss = 0.0f;
    if (h < H) {
      float qr[8];
#pragma unroll
      for (int j = 0; j < 8; ++j) qr[j] = ql[h * 9 + j];
      for (int g = gb; g < ge; ++g) {
        if (g == h) continue;
        const float4 k0 = *(const float4*)(kl + g * 8);
        const float4 k1 = *(const float4*)(kl + g * 8 + 4);
        float dot = qr[0] * k0.x;
        dot = fmaf(qr[1], k0.y, dot);
        dot = fmaf(qr[2], k0.z, dot);
        dot = fmaf(qr[3], k0.w, dot);
        dot = fmaf(qr[4], k1.x, dot);
        dot = fmaf(qr[5], k1.y, dot);
        dot = fmaf(qr[6], k1.z, dot);
        dot = fmaf(qr[7], k1.w, dot);
        const int d = h - g;
        const float e = __expf(-(float)(d * d) * INVH2) * dot;
        const float mn = fmaxf(m, e);
        ss = ss * __expf(m - mn) + __expf(e - mn);
        m = mn;
      }
    }
    mrgm[s][hs] = m;
    mrgs[s][hs] = ss;
    __syncthreads();
    if (s == 0 && h < H) {
      const float M = fmaxf(fmaxf(mrgm[0][hs], mrgm[1][hs]),
                            fmaxf(mrgm[2][hs], mrgm[3][hs]));
      float S = 0.0f;
#pragma unroll
      for (int j = 0; j < 4; ++j) S += mrgs[j][hs] * __expf(mrgm[j][hs] - M);
      mh[((size_t)b * W + w) * H + h] = M;
      sh[((size_t)b * W + w) * H + h] = S;
    }
    __syncthreads();
  }
}

// ---------------------------------------------------------------------------
// K2b: per-(b,h) row softmax stats over src w (no mask). mw/sw layout [b][h][w].
// ---------------------------------------------------------------------------
__global__ __launch_bounds__(256)
void k_rowstats(const float* __restrict__ q, const float* __restrict__ k,
                float* __restrict__ mw, float* __restrict__ sw) {
  const int h = blockIdx.x, b = blockIdx.y;
  __shared__ float ql[W * 9];
  __shared__ __align__(16) float kl[W * CQ];
  __shared__ float mrgm[4][64], mrgs[4][64];
  const int tid = threadIdx.x;
  const float* qrow = q + (size_t)b * CQ * HW + (size_t)h * W;
  const float* krow = k + (size_t)b * CQ * HW + (size_t)h * W;
  for (int i = tid; i < W * CQ; i += 256) {
    const int o = i / W, ww = i - o * W;
    ql[ww * 9 + o] = qrow[(size_t)o * HW + ww];
    kl[ww * 8 + o] = krow[(size_t)o * HW + ww];
  }
  __syncthreads();
  const int s = tid >> 6, ws0 = tid & 63;
  const int gb = s * 120, ge = gb + 120;
  for (int it = 0; it < 8; ++it) {
    const int ww = ws0 + it * 64;
    float m = -INFINITY, ss = 0.0f;
    if (ww < W) {
      float qr[8];
#pragma unroll
      for (int j = 0; j < 8; ++j) qr[j] = ql[ww * 9 + j];
      for (int g = gb; g < ge; ++g) {
        const float4 k0 = *(const float4*)(kl + g * 8);
        const float4 k1 = *(const float4*)(kl + g * 8 + 4);
        float dot = qr[0] * k0.x;
        dot = fmaf(qr[1], k0.y, dot);
        dot = fmaf(qr[2], k0.z, dot);
        dot = fmaf(qr[3], k0.w, dot);
        dot = fmaf(qr[4], k1.x, dot);
        dot = fmaf(qr[5], k1.y, dot);
        dot = fmaf(qr[6], k1.z, dot);
        dot = fmaf(qr[7], k1.w, dot);
        const int d = ww - g;
        const float e = __expf(-(float)(d * d) * INVW2) * dot;
        const float mn = fmaxf(m, e);
        ss = ss * __expf(m - mn) + __expf(e - mn);
        m = mn;
      }
    }
    mrgm[s][ws0] = m;
    mrgs[s][ws0] = ss;
    __syncthreads();
    if (s == 0 && ww < W) {
      const float M = fmaxf(fmaxf(mrgm[0][ws0], mrgm[1][ws0]),
                            fmaxf(mrgm[2][ws0], mrgm[3][ws0]));
      float S = 0.0f;
#pragma unroll
      for (int j = 0; j < 4; ++j) S += mrgs[j][ws0] * __expf(mrgm[j][ws0] - M);
      mw[((size_t)b * H + h) * W + ww] = M;
      sw[((size_t)b * H + h) * W + ww] = S;
    }
    __syncthreads();
  }
}

// ---------------------------------------------------------------------------
// K3a: per-(b,w) column aggregation: out_h[c,h] = sum_g att_h[h,g] * v[c,g,w].
// att recomputed on the fly in 8-wide g chunks into LDS; 4c x 4h register tile.
// Output oht layout [b][w][c][h] (bf16).
// ---------------------------------------------------------------------------
__global__ __launch_bounds__(512)
void k_outh(const float* __restrict__ qt, const float* __restrict__ kt,
            const unsigned short* __restrict__ vt,
            const float* __restrict__ mh, const float* __restrict__ sh,
            const float* __restrict__ mw, const float* __restrict__ sw,
            unsigned short* __restrict__ oht) {
  const int w = blockIdx.x, b = blockIdx.y;
  __shared__ float ql[H * 9];
  __shared__ __align__(16) float kl[H * CQ];
  __shared__ float ml[272], zl[272];
  __shared__ __align__(16) float attl[8 * 272];
  __shared__ __align__(16) float vcl[8 * 68];
  const int tid = threadIdx.x;
  const float* qcol = qt + (((size_t)b * W + w) * H) * CQ;
  const float* kcol = kt + (((size_t)b * W + w) * H) * CQ;
  for (int i = tid; i < H * CQ; i += 512) {
    ql[(i >> 3) * 9 + (i & 7)] = qcol[i];
    kl[i] = kcol[i];
  }
  if (tid < H) {
    const float Mh = mh[((size_t)b * W + w) * H + tid];
    const float Sh = sh[((size_t)b * W + w) * H + tid];
    const float Mw = mw[((size_t)b * H + tid) * W + w];
    const float Sw = sw[((size_t)b * H + tid) * W + w];
    const float M = fmaxf(Mh, Mw);
    const float Z = Sh * __expf(Mh - M) + Sw * __expf(Mw - M);
    ml[tid] = M;
    zl[tid] = 1.0f / Z;
  } else if (tid < 272) {
    ml[tid] = 0.0f;
    zl[tid] = 0.0f;
  }
  __syncthreads();
  const int cg = tid & 15, hg = tid >> 4;  // 16 c-groups x 32 h-groups
  const int c0 = cg * 4;
  const int nt = (hg < 4) ? 3 : 2;  // h-tiles hg, hg+32, (hg+64 if < 68)
  float acc[3][4][4];
#pragma unroll
  for (int t = 0; t < 3; ++t)
#pragma unroll
    for (int i = 0; i < 4; ++i)
#pragma unroll
      for (int j = 0; j < 4; ++j) acc[t][i][j] = 0.0f;
  const unsigned short* vtb = vt + (((size_t)b * W + w) * H) * C;
  for (int gc = 0; gc < H; gc += 8) {
    {
      const int gl = tid >> 6, c = tid & 63;
      const int g = gc + gl;
      vcl[gl * 68 + c] = (g < H) ? bits2f(vtb[(size_t)g * C + c]) : 0.0f;
    }
    for (int idx = tid; idx < 8 * 272; idx += 512) {
      const int gl = idx / 272, hh = idx - gl * 272;
      const int g = gc + gl;
      float a = 0.0f;
      if (hh < H && g < H && g != hh) {
        const float* qr = ql + hh * 9;
        const float4 k0 = *(const float4*)(kl + g * 8);
        const float4 k1 = *(const float4*)(kl + g * 8 + 4);
        float dot = qr[0] * k0.x;
        dot = fmaf(qr[1], k0.y, dot);
        dot = fmaf(qr[2], k0.z, dot);
        dot = fmaf(qr[3], k0.w, dot);
        dot = fmaf(qr[4], k1.x, dot);
        dot = fmaf(qr[5], k1.y, dot);
        dot = fmaf(qr[6], k1.z, dot);
        dot = fmaf(qr[7], k1.w, dot);
        const int d = hh - g;
        const float e = __expf(-(float)(d * d) * INVH2) * dot;
        a = __expf(e - ml[hh]) * zl[hh];
      }
      attl[idx] = a;
    }
    __syncthreads();
#pragma unroll
    for (int t = 0; t < 3; ++t) {
      if (t < nt) {
        const int h0 = (hg + t * 32) * 4;
#pragma unroll
        for (int gl = 0; gl < 8; ++gl) {
          const float4 a4 = *(const float4*)(attl + gl * 272 + h0);
          const float4 v4 = *(const float4*)(vcl + gl * 68 + c0);
          acc[t][0][0] = fmaf(a4.x, v4.x, acc[t][0][0]);
          acc[t][0][1] = fmaf(a4.x, v4.y, acc[t][0][1]);
          acc[t][0][2] = fmaf(a4.x, v4.z, acc[t][0][2]);
          acc[t][0][3] = fmaf(a4.x, v4.w, acc[t][0][3]);
          acc[t][1][0] = fmaf(a4.y, v4.x, acc[t][1][0]);
          acc[t][1][1] = fmaf(a4.y, v4.y, acc[t][1][1]);
          acc[t][1][2] = fmaf(a4.y, v4.z, acc[t][1][2]);
          acc[t][1][3] = fmaf(a4.y, v4.w, acc[t][1][3]);
          acc[t][2][0] = fmaf(a4.z, v4.x, acc[t][2][0]);
          acc[t][2][1] = fmaf(a4.z, v4.y, acc[t][2][1]);
          acc[t][2][2] = fmaf(a4.z, v4.z, acc[t][2][2]);
          acc[t][2][3] = fmaf(a4.z, v4.w, acc[t][2][3]);
          acc[t][3][0] = fmaf(a4.w, v4.x, acc[t][3][0]);
          acc[t][3][1] = fmaf(a4.w, v4.y, acc[t][3][1]);
          acc[t][3][2] = fmaf(a4.w, v4.z, acc[t][3][2]);
          acc[t][3][3] = fmaf(a4.w, v4.w, acc[t][3][3]);
        }
      }
    }
    __syncthreads();
  }
  unsigned short* ob = oht + (((size_t)b * W + w) * C) * H;
#pragma unroll
  for (int t = 0; t < 3; ++t) {
    if (t < nt) {
      const int h0 = (hg + t * 32) * 4;
#pragma unroll
      for (int ci = 0; ci < 4; ++ci) {
        unsigned short* p = ob + (size_t)(c0 + ci) * H + h0;
        ushort2 u0;
        u0.x = f2bf(acc[t][0][ci]);
        u0.y = f2bf(acc[t][1][ci]);
        *(ushort2*)p = u0;
        if (h0 + 3 < H) {
          ushort2 u1;
          u1.x = f2bf(acc[t][2][ci]);
          u1.y = f2bf(acc[t][3][ci]);
          *(ushort2*)(p + 2) = u1;
        }
      }
    }
  }
}

// ---------------------------------------------------------------------------
// K3b: per-(b,h) row aggregation: out_w[c,w] = sum_s att_w[w,s] * v[c,h,s].
// Output ow layout [b][h][c][w] (bf16).
// ---------------------------------------------------------------------------
__global__ __launch_bounds__(512)
void k_outw(const float* __restrict__ q, const float* __restrict__ k,
            const unsigned short* __restrict__ v,
            const float* __restrict__ mh, const float* __restrict__ sh,
            const float* __restrict__ mw, const float* __restrict__ sw,
            unsigned short* __restrict__ ow) {
  const int h = blockIdx.x, b = blockIdx.y;
  __shared__ float ql[W * 9];
  __shared__ __align__(16) float kl[W * CQ];
  __shared__ float ml[W], zl[W];
  __shared__ __align__(16) float attl[8 * W];
  __shared__ __align__(16) float vcl[8 * 68];
  const int tid = threadIdx.x;
  const float* qrow = q + (size_t)b * CQ * HW + (size_t)h * W;
  const float* krow = k + (size_t)b * CQ * HW + (size_t)h * W;
  for (int i = tid; i < W * CQ; i += 512) {
    const int o = i / W, ww = i - o * W;
    ql[ww * 9 + o] = qrow[(size_t)o * HW + ww];
    kl[ww * 8 + o] = krow[(size_t)o * HW + ww];
  }
  if (tid < W) {
    const float Mh = mh[((size_t)b * W + tid) * H + h];
    const float Sh = sh[((size_t)b * W + tid) * H + h];
    const float Mw = mw[((size_t)b * H + h) * W + tid];
    const float Sw = sw[((size_t)b * H + h) * W + tid];
    const float M = fmaxf(Mh, Mw);
    const float Z = Sh * __expf(Mh - M) + Sw * __expf(Mw - M);
    ml[tid] = M;
    zl[tid] = 1.0f / Z;
  }
  __syncthreads();
  const int cg = tid & 15, wg = tid >> 4;
  const int c0 = cg * 4;
  const int nt = (wg < 24) ? 4 : 3;  // w-tiles wg, wg+32, wg+64, (wg+96 if <120)
  float acc[4][4][4];
#pragma unroll
  for (int t = 0; t < 4; ++t)
#pragma unroll
    for (int i = 0; i < 4; ++i)
#pragma unroll
      for (int j = 0; j < 4; ++j) acc[t][i][j] = 0.0f;
  const unsigned short* vrow = v + (size_t)b * C * HW + (size_t)h * W;
  for (int sc = 0; sc < W; sc += 8) {
    {
      const int c = tid >> 3, sl = tid & 7;
      vcl[sl * 68 + c] = bits2f(vrow[(size_t)c * HW + sc + sl]);
    }
    for (int idx = tid; idx < 8 * W; idx += 512) {
      const int gl = idx / W, wd = idx - gl * W;
      const int g = sc + gl;
      const float* qr = ql + wd * 9;
      const float4 k0 = *(const float4*)(kl + g * 8);
      const float4 k1 = *(const float4*)(kl + g * 8 + 4);
      float dot = qr[0] * k0.x;
      dot = fmaf(qr[1], k0.y, dot);
      dot = fmaf(qr[2], k0.z, dot);
      dot = fmaf(qr[3], k0.w, dot);
      dot = fmaf(qr[4], k1.x, dot);
      dot = fmaf(qr[5], k1.y, dot);
      dot = fmaf(qr[6], k1.z, dot);
      dot = fmaf(qr[7], k1.w, dot);
      const int d = wd - g;
      const float e = __expf(-(float)(d * d) * INVW2) * dot;
      attl[idx] = __expf(e - ml[wd]) * zl[wd];
    }
    __syncthreads();
#pragma unroll
    for (int t = 0; t < 4; ++t) {
      if (t < nt) {
        const int w0 = (wg + t * 32) * 4;
#pragma unroll
        for (int gl = 0; gl < 8; ++gl) {
          const float4 a4 = *(const float4*)(attl + gl * W + w0);
          const float4 v4 = *(const float4*)(vcl + gl * 68 + c0);
          acc[t][0][0] = fmaf(a4.x, v4.x, acc[t][0][0]);
          acc[t][0][1] = fmaf(a4.x, v4.y, acc[t][0][1]);
          acc[t][0][2] = fmaf(a4.x, v4.z, acc[t][0][2]);
          acc[t][0][3] = fmaf(a4.x, v4.w, acc[t][0][3]);
          acc[t][1][0] = fmaf(a4.y, v4.x, acc[t][1][0]);
          acc[t][1][1] = fmaf(a4.y, v4.y, acc[t][1][1]);
          acc[t][1][2] = fmaf(a4.y, v4.z, acc[t][1][2]);
          acc[t][1][3] = fmaf(a4.y, v4.w, acc[t][1][3]);
          acc[t][2][0] = fmaf(a4.z, v4.x, acc[t][2][0]);
          acc[t][2][1] = fmaf(a4.z, v4.y, acc[t][2][1]);
          acc[t][2][2] = fmaf(a4.z, v4.z, acc[t][2][2]);
          acc[t][2][3] = fmaf(a4.z, v4.w, acc[t][2][3]);
          acc[t][3][0] = fmaf(a4.w, v4.x, acc[t][3][0]);
          acc[t][3][1] = fmaf(a4.w, v4.y, acc[t][3][1]);
          acc[t][3][2] = fmaf(a4.w, v4.z, acc[t][3][2]);
          acc[t][3][3] = fmaf(a4.w, v4.w, acc[t][3][3]);
        }
      }
    }
    __syncthreads();
  }
  unsigned short* ob = ow + (((size_t)b * H + h) * C) * W;
#pragma unroll
  for (int t = 0; t < 4; ++t) {
    if (t < nt) {
      const int w0 = (wg + t * 32) * 4;
#pragma unroll
      for (int ci = 0; ci < 4; ++ci) {
        ushort4 u;
        u.x = f2bf(acc[t][0][ci]);
        u.y = f2bf(acc[t][1][ci]);
        u.z = f2bf(acc[t][2][ci]);
        u.w = f2bf(acc[t][3][ci]);
        *(ushort4*)(ob + (size_t)(c0 + ci) * W + w0) = u;
      }
    }
  }
}

// ---------------------------------------------------------------------------
// K4: out = gamma*(out_h + out_w) + x, with LDS tile transpose for oht.
// ---------------------------------------------------------------------------
__global__ __launch_bounds__(256)
void k_combine(const unsigned short* __restrict__ oht,
               const unsigned short* __restrict__ ow,
               const float* __restrict__ x,
               const float* __restrict__ gp,
               float* __restrict__ out) {
  __shared__ float tile[32][33];
  const int b = blockIdx.z >> 6, c = blockIdx.z & 63;
  const int w0 = blockIdx.x * 32, h0 = blockIdx.y * 32;
  const int tx = threadIdx.x, ty = threadIdx.y;  // (32, 8)
#pragma unroll
  for (int i = 0; i < 4; ++i) {
    const int wl = ty + i * 8;
    const int hh = h0 + tx;
    float val = 0.0f;
    if (hh < H) val = bits2f(oht[(((size_t)b * W + (w0 + wl)) * C + c) * H + hh]);
    tile[wl][tx] = val;
  }
  __syncthreads();
  const float gamma = *gp;
#pragma unroll
  for (int i = 0; i < 4; ++i) {
    const int hl = ty + i * 8;
    const int hh = h0 + hl;
    if (hh < H) {
      const int ww = w0 + tx;
      const float oh = tile[tx][hl];
      const float owv = bits2f(ow[(((size_t)b * H + hh) * C + c) * W + ww]);
      const size_t xi = ((size_t)b * C + c) * HW + (size_t)hh * W + ww;
      out[xi] = fmaf(gamma, oh + owv, x[xi]);
    }
  }
}

}  // namespace

extern "C" void kernel_launch(void* const* d_in, const int* in_sizes, int n_in,
                              void* d_out, int out_size, void* d_ws, size_t ws_size,
                              hipStream_t stream) {
  (void)in_sizes; (void)n_in; (void)out_size; (void)ws_size;
  const float* x  = (const float*)d_in[0];
  const float* Wq = (const float*)d_in[1];
  const float* bq = (const float*)d_in[2];
  const float* Wk = (const float*)d_in[3];
  const float* bk = (const float*)d_in[4];
  const float* Wv = (const float*)d_in[5];
  const float* bv = (const float*)d_in[6];
  const float* gp = (const float*)d_in[7];
  float* out = (float*)d_out;

  char* p = (char*)d_ws;
  auto take = [&](size_t bytes) -> void* {
    char* r = p;
    p += (bytes + 255) & ~(size_t)255;
    return (void*)r;
  };
  float* q  = (float*)take(sizeof(float) * (size_t)B * CQ * HW);
  float* k  = (float*)take(sizeof(float) * (size_t)B * CQ * HW);
  float* qt = (float*)take(sizeof(float) * (size_t)B * CQ * HW);
  float* kt = (float*)take(sizeof(float) * (size_t)B * CQ * HW);
  float* mh = (float*)take(sizeof(float) * (size_t)B * HW);
  float* sh = (float*)take(sizeof(float) * (size_t)B * HW);
  float* mw = (float*)take(sizeof(float) * (size_t)B * HW);
  float* sw = (float*)take(sizeof(float) * (size_t)B * HW);
  unsigned short* v   = (unsigned short*)take(sizeof(unsigned short) * (size_t)B * C * HW);
  unsigned short* vt  = (unsigned short*)take(sizeof(unsigned short) * (size_t)B * C * HW);
  unsigned short* oht = (unsigned short*)take(sizeof(unsigned short) * (size_t)B * C * HW);
  unsigned short* owb = (unsigned short*)take(sizeof(unsigned short) * (size_t)B * C * HW);

  hipLaunchKernelGGL(k_qkv, dim3((B * HW + 255) / 256), dim3(256), 0, stream,
                     x, Wq, bq, Wk, bk, Wv, bv, q, k, qt, kt, v, vt);
  hipLaunchKernelGGL(k_colstats, dim3(W, B), dim3(256), 0, stream, qt, kt, mh, sh);
  hipLaunchKernelGGL(k_rowstats, dim3(H, B), dim3(256), 0, stream, q, k, mw, sw);
  hipLaunchKernelGGL(k_outh, dim3(W, B), dim3(512), 0, stream, qt, kt, vt, mh, sh, mw, sw, oht);
  hipLaunchKernelGGL(k_outw, dim3(H, B), dim3(512), 0, stream, q, k, v, mh, sh, mw, sw, owb);
  hipLaunchKernelGGL(k_combine, dim3(W / 32, (H + 31) / 32, B * C), dim3(32, 8), 0, stream,
                     oht, owb, x, gp, out);
}

// Round 2
// 692.087 us; speedup vs baseline: 2.8901x; 2.8901x over previous
//
#include <hip/hip_runtime.h>
#include <hip/hip_bf16.h>

namespace {

constexpr int B  = 2;
constexpr int C  = 64;
constexpr int CQ = 8;
constexpr int H  = 270;
constexpr int W  = 480;
constexpr int HW = H * W;
constexpr float INVH2 = 2.0f / (270.0f * 270.0f);  // dw_h = exp(-d^2 * INVH2)
constexpr float INVW2 = 2.0f / (480.0f * 480.0f);

typedef __attribute__((ext_vector_type(4))) float f32x4;
typedef __attribute__((ext_vector_type(8))) short short8;

__device__ __forceinline__ float bits2f(unsigned short u) {
  union { unsigned int i; float f; } cv;
  cv.i = ((unsigned int)u) << 16;
  return cv.f;
}

__device__ __forceinline__ unsigned short f2bf(float f) {
  union { __hip_bfloat16 b; unsigned short u; } cv;
  cv.b = __float2bfloat16(f);
  return cv.u;
}

// ---------------------------------------------------------------------------
// K1: q/k/v 1x1 projections. One thread per pixel. Writes q,k (f32, normal),
// q_t,k_t (f32, [b][w][h][8]), v (bf16 normal), v_t (bf16, [b][w][g][c]).
// ---------------------------------------------------------------------------
__global__ __launch_bounds__(256)
void k_qkv(const float* __restrict__ x,
           const float* __restrict__ Wq, const float* __restrict__ bq,
           const float* __restrict__ Wk, const float* __restrict__ bk,
           const float* __restrict__ Wv, const float* __restrict__ bv,
           float* __restrict__ q, float* __restrict__ k,
           float* __restrict__ qt, float* __restrict__ kt,
           unsigned short* __restrict__ v, unsigned short* __restrict__ vt) {
  __shared__ __align__(16) float wql[CQ * C];
  __shared__ __align__(16) float wkl[CQ * C];
  __shared__ __align__(16) float wvl[C * C];
  __shared__ float bql[CQ], bkl[CQ], bvl[C];
  const int tid = threadIdx.x;
  for (int i = tid; i < CQ * C; i += 256) { wql[i] = Wq[i]; wkl[i] = Wk[i]; }
  for (int i = tid; i < C * C; i += 256) wvl[i] = Wv[i];
  if (tid < CQ) { bql[tid] = bq[tid]; bkl[tid] = bk[tid]; }
  if (tid < C) bvl[tid] = bv[tid];
  __syncthreads();
  const int pix = blockIdx.x * 256 + tid;
  if (pix >= B * HW) return;
  const int b = pix / HW;
  const int r = pix - b * HW;
  const int h = r / W;
  const int w = r - h * W;

  float qa[CQ], ka[CQ], va[C];
#pragma unroll
  for (int o = 0; o < CQ; ++o) { qa[o] = bql[o]; ka[o] = bkl[o]; }
#pragma unroll
  for (int o = 0; o < C; ++o) va[o] = bvl[o];

  const float* xp = x + (size_t)b * C * HW + r;
  for (int c = 0; c < C; c += 4) {
    const float x0 = xp[(size_t)(c + 0) * HW];
    const float x1 = xp[(size_t)(c + 1) * HW];
    const float x2 = xp[(size_t)(c + 2) * HW];
    const float x3 = xp[(size_t)(c + 3) * HW];
#pragma unroll
    for (int o = 0; o < CQ; ++o) {
      const float4 a = *(const float4*)(wql + o * C + c);
      qa[o] = fmaf(a.w, x3, fmaf(a.z, x2, fmaf(a.y, x1, fmaf(a.x, x0, qa[o]))));
      const float4 bb = *(const float4*)(wkl + o * C + c);
      ka[o] = fmaf(bb.w, x3, fmaf(bb.z, x2, fmaf(bb.y, x1, fmaf(bb.x, x0, ka[o]))));
    }
#pragma unroll
    for (int o = 0; o < C; ++o) {
      const float4 cc = *(const float4*)(wvl + o * C + c);
      va[o] = fmaf(cc.w, x3, fmaf(cc.z, x2, fmaf(cc.y, x1, fmaf(cc.x, x0, va[o]))));
    }
  }

  float* qp = q + (size_t)b * CQ * HW + r;
  float* kp = k + (size_t)b * CQ * HW + r;
#pragma unroll
  for (int o = 0; o < CQ; ++o) { qp[(size_t)o * HW] = qa[o]; kp[(size_t)o * HW] = ka[o]; }
  unsigned short* vp = v + (size_t)b * C * HW + r;
#pragma unroll
  for (int o = 0; o < C; ++o) vp[(size_t)o * HW] = f2bf(va[o]);

  float4* qtp = (float4*)(qt + (((size_t)b * W + w) * H + h) * CQ);
  qtp[0] = make_float4(qa[0], qa[1], qa[2], qa[3]);
  qtp[1] = make_float4(qa[4], qa[5], qa[6], qa[7]);
  float4* ktp = (float4*)(kt + (((size_t)b * W + w) * H + h) * CQ);
  ktp[0] = make_float4(ka[0], ka[1], ka[2], ka[3]);
  ktp[1] = make_float4(ka[4], ka[5], ka[6], ka[7]);
  unsigned short* vtp = vt + (((size_t)b * W + w) * H + h) * C;
#pragma unroll
  for (int j = 0; j < 16; ++j) {
    ushort4 u;
    u.x = f2bf(va[4 * j + 0]);
    u.y = f2bf(va[4 * j + 1]);
    u.z = f2bf(va[4 * j + 2]);
    u.w = f2bf(va[4 * j + 3]);
    *(ushort4*)(vtp + 4 * j) = u;
  }
}

// ---------------------------------------------------------------------------
// K2a: per-(b,w) column softmax stats over g (diag h==g masked out).
// mh/sh layout [b][w][h].
// ---------------------------------------------------------------------------
__global__ __launch_bounds__(256)
void k_colstats(const float* __restrict__ qt, const float* __restrict__ kt,
                float* __restrict__ mh, float* __restrict__ sh) {
  const int w = blockIdx.x, b = blockIdx.y;
  __shared__ float ql[H * 9];
  __shared__ __align__(16) float kl[H * CQ];
  __shared__ float mrgm[4][64], mrgs[4][64];
  const int tid = threadIdx.x;
  const float* qcol = qt + (((size_t)b * W + w) * H) * CQ;
  const float* kcol = kt + (((size_t)b * W + w) * H) * CQ;
  for (int i = tid; i < H * CQ; i += 256) {
    ql[(i >> 3) * 9 + (i & 7)] = qcol[i];
    kl[i] = kcol[i];
  }
  __syncthreads();
  const int s = tid >> 6, hs = tid & 63;
  const int gb = s * 68, ge = min(H, gb + 68);
  for (int it = 0; it < 5; ++it) {
    const int h = hs + it * 64;
    float m = -INFINITY, ss = 0.0f;
    if (h < H) {
      float qr[8];
#pragma unroll
      for (int j = 0; j < 8; ++j) qr[j] = ql[h * 9 + j];
      for (int g = gb; g < ge; ++g) {
        if (g == h) continue;
        const float4 k0 = *(const float4*)(kl + g * 8);
        const float4 k1 = *(const float4*)(kl + g * 8 + 4);
        float dot = qr[0] * k0.x;
        dot = fmaf(qr[1], k0.y, dot);
        dot = fmaf(qr[2], k0.z, dot);
        dot = fmaf(qr[3], k0.w, dot);
        dot = fmaf(qr[4], k1.x, dot);
        dot = fmaf(qr[5], k1.y, dot);
        dot = fmaf(qr[6], k1.z, dot);
        dot = fmaf(qr[7], k1.w, dot);
        const int d = h - g;
        const float e = __expf(-(float)(d * d) * INVH2) * dot;
        const float mn = fmaxf(m, e);
        ss = ss * __expf(m - mn) + __expf(e - mn);
        m = mn;
      }
    }
    mrgm[s][hs] = m;
    mrgs[s][hs] = ss;
    __syncthreads();
    if (s == 0 && h < H) {
      const float M = fmaxf(fmaxf(mrgm[0][hs], mrgm[1][hs]),
                            fmaxf(mrgm[2][hs], mrgm[3][hs]));
      float S = 0.0f;
#pragma unroll
      for (int j = 0; j < 4; ++j) S += mrgs[j][hs] * __expf(mrgm[j][hs] - M);
      mh[((size_t)b * W + w) * H + h] = M;
      sh[((size_t)b * W + w) * H + h] = S;
    }
    __syncthreads();
  }
}

// ---------------------------------------------------------------------------
// K2b: per-(b,h) row softmax stats over src w (no mask). mw/sw layout [b][h][w].
// ---------------------------------------------------------------------------
__global__ __launch_bounds__(256)
void k_rowstats(const float* __restrict__ q, const float* __restrict__ k,
                float* __restrict__ mw, float* __restrict__ sw) {
  const int h = blockIdx.x, b = blockIdx.y;
  __shared__ float ql[W * 9];
  __shared__ __align__(16) float kl[W * CQ];
  __shared__ float mrgm[4][64], mrgs[4][64];
  const int tid = threadIdx.x;
  const float* qrow = q + (size_t)b * CQ * HW + (size_t)h * W;
  const float* krow = k + (size_t)b * CQ * HW + (size_t)h * W;
  for (int i = tid; i < W * CQ; i += 256) {
    const int o = i / W, ww = i - o * W;
    ql[ww * 9 + o] = qrow[(size_t)o * HW + ww];
    kl[ww * 8 + o] = krow[(size_t)o * HW + ww];
  }
  __syncthreads();
  const int s = tid >> 6, ws0 = tid & 63;
  const int gb = s * 120, ge = gb + 120;
  for (int it = 0; it < 8; ++it) {
    const int ww = ws0 + it * 64;
    float m = -INFINITY, ss = 0.0f;
    if (ww < W) {
      float qr[8];
#pragma unroll
      for (int j = 0; j < 8; ++j) qr[j] = ql[ww * 9 + j];
      for (int g = gb; g < ge; ++g) {
        const float4 k0 = *(const float4*)(kl + g * 8);
        const float4 k1 = *(const float4*)(kl + g * 8 + 4);
        float dot = qr[0] * k0.x;
        dot = fmaf(qr[1], k0.y, dot);
        dot = fmaf(qr[2], k0.z, dot);
        dot = fmaf(qr[3], k0.w, dot);
        dot = fmaf(qr[4], k1.x, dot);
        dot = fmaf(qr[5], k1.y, dot);
        dot = fmaf(qr[6], k1.z, dot);
        dot = fmaf(qr[7], k1.w, dot);
        const int d = ww - g;
        const float e = __expf(-(float)(d * d) * INVW2) * dot;
        const float mn = fmaxf(m, e);
        ss = ss * __expf(m - mn) + __expf(e - mn);
        m = mn;
      }
    }
    mrgm[s][ws0] = m;
    mrgs[s][ws0] = ss;
    __syncthreads();
    if (s == 0 && ww < W) {
      const float M = fmaxf(fmaxf(mrgm[0][ws0], mrgm[1][ws0]),
                            fmaxf(mrgm[2][ws0], mrgm[3][ws0]));
      float S = 0.0f;
#pragma unroll
      for (int j = 0; j < 4; ++j) S += mrgs[j][ws0] * __expf(mrgm[j][ws0] - M);
      mw[((size_t)b * H + h) * W + ww] = M;
      sw[((size_t)b * H + h) * W + ww] = S;
    }
    __syncthreads();
  }
}

// ---------------------------------------------------------------------------
// K3b: out_w via MFMA. Block = (half, h, b); M=240 (w), N=64 (c), K=480 (s).
// Per 32-wide s-chunk: VALU writes P (bf16, A-frag layout, stride 40) to LDS,
// V staged B-frag-swizzled [k/8][c][k&7]; mfma 16x16x32 accumulates.
// Epilogue: accs -> LDS transpose buf -> coalesced global (ow [b][h][c][w]).
// ---------------------------------------------------------------------------
__global__ __launch_bounds__(512, 4)
void k_outw(const float* __restrict__ q, const float* __restrict__ k,
            const unsigned short* __restrict__ v,
            const float* __restrict__ mh, const float* __restrict__ sh,
            const float* __restrict__ mw, const float* __restrict__ sw,
            unsigned short* __restrict__ ow) {
  constexpr int M = 240;
  constexpr int NT = 15;   // 16-row m-tiles
  constexpr int PS = 40;   // P row stride (bf16): breaks A-frag bank conflicts
  constexpr int OS = 244;  // outbuf row stride (bf16)
  constexpr int OFF_K  = 0;      // f32[480*9]  = 17280 B
  constexpr int OFF_Q  = 17280;  // f32[240*9]  =  8640 B
  constexpr int OFF_P  = 25920;  // bf16[240*40]= 19200 B
  constexpr int OFF_VB = 45120;  // bf16[2048]  =  4096 B
  constexpr int OFF_MZ = 49216;  // f32[240]*2  =  1920 B
  constexpr int OFF_DW = 51136;  // f32[959]    =  3836 B
  __shared__ __align__(16) char smem[54976];
  const int half = blockIdx.x, h = blockIdx.y, b = blockIdx.z;
  const int w0 = half * M;
  const int tid = threadIdx.x;
  float* kf = (float*)(smem + OFF_K);
  float* ql = (float*)(smem + OFF_Q);
  unsigned short* Pb = (unsigned short*)(smem + OFF_P);
  unsigned short* vB = (unsigned short*)(smem + OFF_VB);
  float* ml = (float*)(smem + OFF_MZ);
  float* zl = ml + M;
  float* dwt = (float*)(smem + OFF_DW);

  const float* qg = q + (size_t)b * CQ * HW + (size_t)h * W;
  const float* kg = k + (size_t)b * CQ * HW + (size_t)h * W;
  for (int idx = tid; idx < 480 * 8; idx += 512) {
    const int o = idx / 480, s = idx - o * 480;
    kf[s * 9 + o] = kg[(size_t)o * HW + s];
  }
  for (int idx = tid; idx < M * 8; idx += 512) {
    const int o = idx / M, wl = idx - o * M;
    ql[wl * 9 + o] = qg[(size_t)o * HW + w0 + wl];
  }
  for (int idx = tid; idx < 959; idx += 512) {
    const float d = (float)(idx - 479);
    dwt[idx] = __expf(-(d * d) * INVW2);
  }
  if (tid < M) {
    const int w = w0 + tid;
    const float Mh = mh[((size_t)b * W + w) * H + h];
    const float Sh = sh[((size_t)b * W + w) * H + h];
    const float Mw = mw[((size_t)b * H + h) * W + w];
    const float Sw = sw[((size_t)b * H + h) * W + w];
    const float Mm = fmaxf(Mh, Mw);
    const float Z = Sh * __expf(Mh - Mm) + Sw * __expf(Mw - Mm);
    ml[tid] = Mm;
    zl[tid] = 1.0f / Z;
  }
  __syncthreads();

  const int lane = tid & 63, wv = tid >> 6;
  const int l15 = lane & 15, quad = lane >> 4;
  const int sl = tid & 31, wr0 = tid >> 5;
  const unsigned short* vg = v + (size_t)b * C * HW + (size_t)h * W;
  const int vc = tid >> 3, vk = (tid & 7) * 4;

  f32x4 acc[2][4];
#pragma unroll
  for (int t = 0; t < 2; ++t)
#pragma unroll
    for (int n = 0; n < 4; ++n)
#pragma unroll
      for (int r = 0; r < 4; ++r) acc[t][n][r] = 0.0f;

  for (int sc = 0; sc < 480; sc += 32) {
    // V stage: B-frag swizzle [k/8][c][k&7]
    {
      const ushort4 vv = *(const ushort4*)(vg + (size_t)vc * HW + sc + vk);
      *(ushort4*)(vB + ((vk >> 3) * 64 + vc) * 8 + (vk & 7)) = vv;
    }
    // P = exp(e - m) * zinv, written in A-frag layout
    {
      float kr[8];
      const int s = sc + sl;
#pragma unroll
      for (int j = 0; j < 8; ++j) kr[j] = kf[s * 9 + j];
#pragma unroll
      for (int jj = 0; jj < 15; ++jj) {
        const int wl = wr0 + 16 * jj;
        const float* qr = ql + wl * 9;
        float dot = qr[0] * kr[0];
        dot = fmaf(qr[1], kr[1], dot);
        dot = fmaf(qr[2], kr[2], dot);
        dot = fmaf(qr[3], kr[3], dot);
        dot = fmaf(qr[4], kr[4], dot);
        dot = fmaf(qr[5], kr[5], dot);
        dot = fmaf(qr[6], kr[6], dot);
        dot = fmaf(qr[7], kr[7], dot);
        const int d = (w0 + wl) - s;
        const float e = dot * dwt[d + 479];
        const float p = __expf(e - ml[wl]) * zl[wl];
        Pb[wl * PS + sl] = f2bf(p);
      }
    }
    __syncthreads();
    // MFMA: D[w][c] += P[w][k] * V[k][c]
    {
      short8 bfr[4];
#pragma unroll
      for (int n = 0; n < 4; ++n)
        bfr[n] = *(const short8*)(vB + (quad * 64 + n * 16 + l15) * 8);
#pragma unroll
      for (int tt = 0; tt < 2; ++tt) {
        const int mt = wv + 8 * tt;
        if (mt < NT) {
          const short8 a = *(const short8*)(Pb + (mt * 16 + l15) * PS + quad * 8);
#pragma unroll
          for (int n = 0; n < 4; ++n)
            acc[tt][n] = __builtin_amdgcn_mfma_f32_16x16x32_bf16(a, bfr[n], acc[tt][n], 0, 0, 0);
        }
      }
    }
    __syncthreads();
  }
  // Epilogue: accs -> LDS (c-major) -> coalesced global
  unsigned short* ob = (unsigned short*)(smem + OFF_Q);
#pragma unroll
  for (int tt = 0; tt < 2; ++tt) {
    const int mt = wv + 8 * tt;
    if (mt < NT) {
#pragma unroll
      for (int n = 0; n < 4; ++n) {
        const int c = n * 16 + l15;
        ushort4 u;
        u.x = f2bf(acc[tt][n][0]);
        u.y = f2bf(acc[tt][n][1]);
        u.z = f2bf(acc[tt][n][2]);
        u.w = f2bf(acc[tt][n][3]);
        *(ushort4*)(ob + c * OS + mt * 16 + quad * 4) = u;
      }
    }
  }
  __syncthreads();
  unsigned short* og = ow + (((size_t)b * H + h) * C) * W + w0;
  for (int idx = tid; idx < 64 * 120; idx += 512) {
    const int c = idx / 120, wp = idx - c * 120;
    *(unsigned int*)(og + (size_t)c * W + 2 * wp) =
        *(const unsigned int*)(ob + c * OS + 2 * wp);
  }
}

// ---------------------------------------------------------------------------
// K3a: out_h via MFMA. Block = (w, b); M=272 (h, padded), N=64 (c), K=270 (g).
// Same structure as k_outw; diag g==h masked to 0. Output oht [b][w][c][h].
// ---------------------------------------------------------------------------
__global__ __launch_bounds__(512, 4)
void k_outh(const float* __restrict__ qt, const float* __restrict__ kt,
            const unsigned short* __restrict__ vt,
            const float* __restrict__ mh, const float* __restrict__ sh,
            const float* __restrict__ mw, const float* __restrict__ sw,
            unsigned short* __restrict__ oht) {
  constexpr int M = 272;
  constexpr int NT = 17;
  constexpr int PS = 40;
  constexpr int OS = 276;
  constexpr int OFF_K  = 0;      // f32[272*9]  = 9792 B
  constexpr int OFF_Q  = 9792;   // f32[272*9]  = 9792 B
  constexpr int OFF_P  = 19584;  // bf16[272*40]= 21760 B
  constexpr int OFF_VB = 41344;  // bf16[2048]  = 4096 B
  constexpr int OFF_MZ = 45440;  // f32[272]*2  = 2176 B
  constexpr int OFF_DW = 47616;  // f32[539]    = 2156 B
  __shared__ __align__(16) char smem[49776];
  const int w = blockIdx.x, b = blockIdx.y;
  const int tid = threadIdx.x;
  float* kf = (float*)(smem + OFF_K);
  float* ql = (float*)(smem + OFF_Q);
  unsigned short* Pb = (unsigned short*)(smem + OFF_P);
  unsigned short* vB = (unsigned short*)(smem + OFF_VB);
  float* ml = (float*)(smem + OFF_MZ);
  float* zl = ml + M;
  float* dwt = (float*)(smem + OFF_DW);

  const float* qtb = qt + (((size_t)b * W + w) * H) * CQ;
  const float* ktb = kt + (((size_t)b * W + w) * H) * CQ;
  for (int idx = tid; idx < M * 8; idx += 512) {
    const int hl = idx >> 3, o = idx & 7;
    const float qv = (hl < H) ? qtb[idx] : 0.0f;
    const float kv = (hl < H) ? ktb[idx] : 0.0f;
    ql[hl * 9 + o] = qv;
    kf[hl * 9 + o] = kv;
  }
  for (int idx = tid; idx < 539; idx += 512) {
    const float d = (float)(idx - 269);
    dwt[idx] = __expf(-(d * d) * INVH2);
  }
  if (tid < M) {
    if (tid < H) {
      const float Mh = mh[((size_t)b * W + w) * H + tid];
      const float Sh = sh[((size_t)b * W + w) * H + tid];
      const float Mw = mw[((size_t)b * H + tid) * W + w];
      const float Sw = sw[((size_t)b * H + tid) * W + w];
      const float Mm = fmaxf(Mh, Mw);
      const float Z = Sh * __expf(Mh - Mm) + Sw * __expf(Mw - Mm);
      ml[tid] = Mm;
      zl[tid] = 1.0f / Z;
    } else {
      ml[tid] = 0.0f;
      zl[tid] = 0.0f;
    }
  }
  __syncthreads();

  const int lane = tid & 63, wv = tid >> 6;
  const int l15 = lane & 15, quad = lane >> 4;
  const int sl = tid & 31, hr0 = tid >> 5;
  const unsigned short* vtb = vt + (((size_t)b * W + w) * H) * C;
  const int vgl = tid >> 4, vc4 = (tid & 15) * 4;

  f32x4 acc[3][4];
#pragma unroll
  for (int t = 0; t < 3; ++t)
#pragma unroll
    for (int n = 0; n < 4; ++n)
#pragma unroll
      for (int r = 0; r < 4; ++r) acc[t][n][r] = 0.0f;

  for (int gc = 0; gc < 288; gc += 32) {
    // V stage
    {
      const int g = gc + vgl;
      ushort4 vv = make_ushort4(0, 0, 0, 0);
      if (g < H) vv = *(const ushort4*)(vtb + (size_t)g * C + vc4);
      unsigned short* base = vB + ((vgl >> 3) * 64 + vc4) * 8 + (vgl & 7);
      base[0]  = vv.x;
      base[8]  = vv.y;
      base[16] = vv.z;
      base[24] = vv.w;
    }
    // P
    {
      float kr[8];
      const int g = gc + sl;
      if (g < H) {
#pragma unroll
        for (int j = 0; j < 8; ++j) kr[j] = kf[g * 9 + j];
      } else {
#pragma unroll
        for (int j = 0; j < 8; ++j) kr[j] = 0.0f;
      }
#pragma unroll
      for (int jj = 0; jj < 17; ++jj) {
        const int hl = hr0 + 16 * jj;
        float p = 0.0f;
        if (hl < H && g < H && g != hl) {
          const float* qr = ql + hl * 9;
          float dot = qr[0] * kr[0];
          dot = fmaf(qr[1], kr[1], dot);
          dot = fmaf(qr[2], kr[2], dot);
          dot = fmaf(qr[3], kr[3], dot);
          dot = fmaf(qr[4], kr[4], dot);
          dot = fmaf(qr[5], kr[5], dot);
          dot = fmaf(qr[6], kr[6], dot);
          dot = fmaf(qr[7], kr[7], dot);
          const int d = hl - g;
          const float e = dot * dwt[d + 269];
          p = __expf(e - ml[hl]) * zl[hl];
        }
        Pb[hl * PS + sl] = f2bf(p);
      }
    }
    __syncthreads();
    // MFMA
    {
      short8 bfr[4];
#pragma unroll
      for (int n = 0; n < 4; ++n)
        bfr[n] = *(const short8*)(vB + (quad * 64 + n * 16 + l15) * 8);
#pragma unroll
      for (int tt = 0; tt < 3; ++tt) {
        const int mt = wv + 8 * tt;
        if (mt < NT) {
          const short8 a = *(const short8*)(Pb + (mt * 16 + l15) * PS + quad * 8);
#pragma unroll
          for (int n = 0; n < 4; ++n)
            acc[tt][n] = __builtin_amdgcn_mfma_f32_16x16x32_bf16(a, bfr[n], acc[tt][n], 0, 0, 0);
        }
      }
    }
    __syncthreads();
  }
  // Epilogue
  unsigned short* ob = (unsigned short*)(smem + OFF_Q);
#pragma unroll
  for (int tt = 0; tt < 3; ++tt) {
    const int mt = wv + 8 * tt;
    if (mt < NT) {
#pragma unroll
      for (int n = 0; n < 4; ++n) {
        const int c = n * 16 + l15;
        ushort4 u;
        u.x = f2bf(acc[tt][n][0]);
        u.y = f2bf(acc[tt][n][1]);
        u.z = f2bf(acc[tt][n][2]);
        u.w = f2bf(acc[tt][n][3]);
        *(ushort4*)(ob + c * OS + mt * 16 + quad * 4) = u;
      }
    }
  }
  __syncthreads();
  unsigned short* og = oht + (((size_t)b * W + w) * C) * H;
  for (int idx = tid; idx < 64 * 135; idx += 512) {
    const int c = idx / 135, hp = idx - c * 135;
    *(unsigned int*)(og + (size_t)c * H + 2 * hp) =
        *(const unsigned int*)(ob + c * OS + 2 * hp);
  }
}

// ---------------------------------------------------------------------------
// K4: out = gamma*(out_h + out_w) + x, with LDS tile transpose for oht.
// ---------------------------------------------------------------------------
__global__ __launch_bounds__(256)
void k_combine(const unsigned short* __restrict__ oht,
               const unsigned short* __restrict__ ow,
               const float* __restrict__ x,
               const float* __restrict__ gp,
               float* __restrict__ out) {
  __shared__ float tile[32][33];
  const int b = blockIdx.z >> 6, c = blockIdx.z & 63;
  const int w0 = blockIdx.x * 32, h0 = blockIdx.y * 32;
  const int tx = threadIdx.x, ty = threadIdx.y;  // (32, 8)
#pragma unroll
  for (int i = 0; i < 4; ++i) {
    const int wl = ty + i * 8;
    const int hh = h0 + tx;
    float val = 0.0f;
    if (hh < H) val = bits2f(oht[(((size_t)b * W + (w0 + wl)) * C + c) * H + hh]);
    tile[wl][tx] = val;
  }
  __syncthreads();
  const float gamma = *gp;
#pragma unroll
  for (int i = 0; i < 4; ++i) {
    const int hl = ty + i * 8;
    const int hh = h0 + hl;
    if (hh < H) {
      const int ww = w0 + tx;
      const float oh = tile[tx][hl];
      const float owv = bits2f(ow[(((size_t)b * H + hh) * C + c) * W + ww]);
      const size_t xi = ((size_t)b * C + c) * HW + (size_t)hh * W + ww;
      out[xi] = fmaf(gamma, oh + owv, x[xi]);
    }
  }
}

}  // namespace

extern "C" void kernel_launch(void* const* d_in, const int* in_sizes, int n_in,
                              void* d_out, int out_size, void* d_ws, size_t ws_size,
                              hipStream_t stream) {
  (void)in_sizes; (void)n_in; (void)out_size; (void)ws_size;
  const float* x  = (const float*)d_in[0];
  const float* Wq = (const float*)d_in[1];
  const float* bq = (const float*)d_in[2];
  const float* Wk = (const float*)d_in[3];
  const float* bk = (const float*)d_in[4];
  const float* Wv = (const float*)d_in[5];
  const float* bv = (const float*)d_in[6];
  const float* gp = (const float*)d_in[7];
  float* out = (float*)d_out;

  char* p = (char*)d_ws;
  auto take = [&](size_t bytes) -> void* {
    char* r = p;
    p += (bytes + 255) & ~(size_t)255;
    return (void*)r;
  };
  float* q  = (float*)take(sizeof(float) * (size_t)B * CQ * HW);
  float* k  = (float*)take(sizeof(float) * (size_t)B * CQ * HW);
  float* qt = (float*)take(sizeof(float) * (size_t)B * CQ * HW);
  float* kt = (float*)take(sizeof(float) * (size_t)B * CQ * HW);
  float* mh = (float*)take(sizeof(float) * (size_t)B * HW);
  float* sh = (float*)take(sizeof(float) * (size_t)B * HW);
  float* mw = (float*)take(sizeof(float) * (size_t)B * HW);
  float* sw = (float*)take(sizeof(float) * (size_t)B * HW);
  unsigned short* v   = (unsigned short*)take(sizeof(unsigned short) * (size_t)B * C * HW);
  unsigned short* vt  = (unsigned short*)take(sizeof(unsigned short) * (size_t)B * C * HW);
  unsigned short* oht = (unsigned short*)take(sizeof(unsigned short) * (size_t)B * C * HW);
  unsigned short* owb = (unsigned short*)take(sizeof(unsigned short) * (size_t)B * C * HW);

  hipLaunchKernelGGL(k_qkv, dim3((B * HW + 255) / 256), dim3(256), 0, stream,
                     x, Wq, bq, Wk, bk, Wv, bv, q, k, qt, kt, v, vt);
  hipLaunchKernelGGL(k_colstats, dim3(W, B), dim3(256), 0, stream, qt, kt, mh, sh);
  hipLaunchKernelGGL(k_rowstats, dim3(H, B), dim3(256), 0, stream, q, k, mw, sw);
  hipLaunchKernelGGL(k_outh, dim3(W, B), dim3(512), 0, stream, qt, kt, vt, mh, sh, mw, sw, oht);
  hipLaunchKernelGGL(k_outw, dim3(2, H, B), dim3(512), 0, stream, q, k, v, mh, sh, mw, sw, owb);
  hipLaunchKernelGGL(k_combine, dim3(W / 32, (H + 31) / 32, B * C), dim3(32, 8), 0, stream,
                     oht, owb, x, gp, out);
}

// Round 3
// 496.456 us; speedup vs baseline: 4.0289x; 1.3941x over previous
//
#include <hip/hip_runtime.h>
#include <hip/hip_bf16.h>

namespace {

constexpr int B  = 2;
constexpr int C  = 64;
constexpr int CQ = 8;
constexpr int H  = 270;
constexpr int W  = 480;
constexpr int HW = H * W;
constexpr float INVH2 = 2.0f / (270.0f * 270.0f);  // dw_h = exp(-d^2 * INVH2)
constexpr float INVW2 = 2.0f / (480.0f * 480.0f);

typedef __attribute__((ext_vector_type(4))) float f32x4;
typedef __attribute__((ext_vector_type(8))) short short8;

__device__ __forceinline__ float bits2f(unsigned short u) {
  union { unsigned int i; float f; } cv;
  cv.i = ((unsigned int)u) << 16;
  return cv.f;
}

__device__ __forceinline__ unsigned short f2bf(float f) {
  union { __hip_bfloat16 b; unsigned short u; } cv;
  cv.b = __float2bfloat16(f);
  return cv.u;
}

__device__ __forceinline__ unsigned int pack2(float a, float b) {
  return ((unsigned int)f2bf(b) << 16) | (unsigned int)f2bf(a);
}

// ---------------------------------------------------------------------------
// K1: q/k/v 1x1 projections. One thread per pixel. Writes bf16 packs:
// qwp/kwp [b][h][w][8], qhp/khp [b][w][h][8], v [b][c][h][w], vt [b][w][h][c].
// ---------------------------------------------------------------------------
__global__ __launch_bounds__(256)
void k_qkv(const float* __restrict__ x,
           const float* __restrict__ Wq, const float* __restrict__ bq,
           const float* __restrict__ Wk, const float* __restrict__ bk,
           const float* __restrict__ Wv, const float* __restrict__ bv,
           unsigned short* __restrict__ qwp, unsigned short* __restrict__ kwp,
           unsigned short* __restrict__ qhp, unsigned short* __restrict__ khp,
           unsigned short* __restrict__ v, unsigned short* __restrict__ vt) {
  __shared__ __align__(16) float wql[CQ * C];
  __shared__ __align__(16) float wkl[CQ * C];
  __shared__ __align__(16) float wvl[C * C];
  __shared__ float bql[CQ], bkl[CQ], bvl[C];
  const int tid = threadIdx.x;
  for (int i = tid; i < CQ * C; i += 256) { wql[i] = Wq[i]; wkl[i] = Wk[i]; }
  for (int i = tid; i < C * C; i += 256) wvl[i] = Wv[i];
  if (tid < CQ) { bql[tid] = bq[tid]; bkl[tid] = bk[tid]; }
  if (tid < C) bvl[tid] = bv[tid];
  __syncthreads();
  const int pix = blockIdx.x * 256 + tid;
  if (pix >= B * HW) return;
  const int b = pix / HW;
  const int r = pix - b * HW;
  const int h = r / W;
  const int w = r - h * W;

  float qa[CQ], ka[CQ], va[C];
#pragma unroll
  for (int o = 0; o < CQ; ++o) { qa[o] = bql[o]; ka[o] = bkl[o]; }
#pragma unroll
  for (int o = 0; o < C; ++o) va[o] = bvl[o];

  const float* xp = x + (size_t)b * C * HW + r;
  for (int c = 0; c < C; c += 4) {
    const float x0 = xp[(size_t)(c + 0) * HW];
    const float x1 = xp[(size_t)(c + 1) * HW];
    const float x2 = xp[(size_t)(c + 2) * HW];
    const float x3 = xp[(size_t)(c + 3) * HW];
#pragma unroll
    for (int o = 0; o < CQ; ++o) {
      const float4 a = *(const float4*)(wql + o * C + c);
      qa[o] = fmaf(a.w, x3, fmaf(a.z, x2, fmaf(a.y, x1, fmaf(a.x, x0, qa[o]))));
      const float4 bb = *(const float4*)(wkl + o * C + c);
      ka[o] = fmaf(bb.w, x3, fmaf(bb.z, x2, fmaf(bb.y, x1, fmaf(bb.x, x0, ka[o]))));
    }
#pragma unroll
    for (int o = 0; o < C; ++o) {
      const float4 cc = *(const float4*)(wvl + o * C + c);
      va[o] = fmaf(cc.w, x3, fmaf(cc.z, x2, fmaf(cc.y, x1, fmaf(cc.x, x0, va[o]))));
    }
  }

  uint4 qp4, kp4;
  qp4.x = pack2(qa[0], qa[1]); qp4.y = pack2(qa[2], qa[3]);
  qp4.z = pack2(qa[4], qa[5]); qp4.w = pack2(qa[6], qa[7]);
  kp4.x = pack2(ka[0], ka[1]); kp4.y = pack2(ka[2], ka[3]);
  kp4.z = pack2(ka[4], ka[5]); kp4.w = pack2(ka[6], ka[7]);
  *(uint4*)(qwp + (size_t)pix * 8) = qp4;
  *(uint4*)(kwp + (size_t)pix * 8) = kp4;
  const size_t tbase = ((size_t)b * W + w) * H + h;
  *(uint4*)(qhp + tbase * 8) = qp4;
  *(uint4*)(khp + tbase * 8) = kp4;

  unsigned short* vp = v + (size_t)b * C * HW + r;
#pragma unroll
  for (int o = 0; o < C; ++o) vp[(size_t)o * HW] = f2bf(va[o]);
  unsigned short* vtp = vt + tbase * C;
#pragma unroll
  for (int j = 0; j < 16; ++j) {
    ushort4 u;
    u.x = f2bf(va[4 * j + 0]);
    u.y = f2bf(va[4 * j + 1]);
    u.z = f2bf(va[4 * j + 2]);
    u.w = f2bf(va[4 * j + 3]);
    *(ushort4*)(vtp + 4 * j) = u;
  }
}

// ---------------------------------------------------------------------------
// K2: out_w unnormalized + S_w. Block=(quarter,h,b), 512 thr, M=128 rows of w.
// Barrier-free K-loop: QK via MFMA (K=8 padded to 32, quads 1-3 zero),
// exp-epilogue in regs, per-wave Pb (A-frag layout), PV via MFMA.
// Outputs: ow [b][h][c][w] (bf16 unnormalized), Sw [b][h][w] (f32 row sums).
// ---------------------------------------------------------------------------
constexpr int PS = 40;    // Pb row stride (elems)
constexpr int VGS = 520;  // vbs group stride (elems): 64*8 + 8 pad

__global__ __launch_bounds__(512, 4)
void k_outw(const unsigned short* __restrict__ qwp,
            const unsigned short* __restrict__ kwp,
            const unsigned short* __restrict__ v,
            unsigned short* __restrict__ ow, float* __restrict__ Sw) {
  __shared__ __align__(16) unsigned short vbs[60 * VGS];  // 62400 B
  __shared__ __align__(16) unsigned short Pb[8 * 16 * PS];  // 10240 B
  const int qx = blockIdx.x, h = blockIdx.y, b = blockIdx.z;
  const int w0 = (qx < 3) ? qx * 128 : 352;
  const int tid = threadIdx.x;

  // stage V row into B-frag-swizzled layout [g/8][c][g&7] (+pad stride)
  const unsigned short* vrow = v + (size_t)b * C * HW + (size_t)h * W;
  for (int idx = tid; idx < 64 * 120; idx += 512) {
    const int c = idx / 120, sq = idx - c * 120;
    const int s = sq * 4;
    const ushort4 vv = *(const ushort4*)(vrow + (size_t)c * HW + s);
    *(ushort4*)(&vbs[(s >> 3) * VGS + c * 8 + (s & 7)]) = vv;
  }

  const int lane = tid & 63, wv = tid >> 6;
  const int l15 = lane & 15, quad = lane >> 4;
  const int r0 = quad * 4;
  const int wrow_base = w0 + wv * 16;

  short8 qa = short8{0, 0, 0, 0, 0, 0, 0, 0};
  if (quad == 0)
    qa = *(const short8*)(qwp + (((size_t)b * H + h) * W + wrow_base + l15) * 8);
  const unsigned short* kRow = kwp + (((size_t)b * H + h) * W) * 8;
  unsigned short* PbW = &Pb[wv * 16 * PS];

  f32x4 acc[4];
  float Sacc[4];
#pragma unroll
  for (int ct = 0; ct < 4; ++ct)
#pragma unroll
    for (int rr = 0; rr < 4; ++rr) acc[ct][rr] = 0.0f;
#pragma unroll
  for (int rr = 0; rr < 4; ++rr) Sacc[rr] = 0.0f;

  __syncthreads();

#pragma unroll
  for (int ci = 0; ci < 15; ++ci) {
    const int sc = ci * 32;
    f32x4 E[2];
#pragma unroll
    for (int nt = 0; nt < 2; ++nt) {
      short8 kb = short8{0, 0, 0, 0, 0, 0, 0, 0};
      if (quad == 0)
        kb = *(const short8*)(kRow + (size_t)(sc + nt * 16 + l15) * 8);
      E[nt] = __builtin_amdgcn_mfma_f32_16x16x32_bf16(
          qa, kb, f32x4{0.f, 0.f, 0.f, 0.f}, 0, 0, 0);
    }
#pragma unroll
    for (int nt = 0; nt < 2; ++nt) {
#pragma unroll
      for (int rr = 0; rr < 4; ++rr) {
        const int wrow = wrow_base + r0 + rr;
        const int scol = sc + nt * 16 + l15;
        const float d = (float)(wrow - scol);
        const float dw = __expf(d * d * (-INVW2));
        const float p = __expf(E[nt][rr] * dw);
        Sacc[rr] += p;
        PbW[(r0 + rr) * PS + nt * 16 + l15] = f2bf(p);
      }
    }
    const short8 pa = *(const short8*)(&PbW[l15 * PS + quad * 8]);
#pragma unroll
    for (int ct = 0; ct < 4; ++ct) {
      const short8 vb =
          *(const short8*)(&vbs[(ci * 4 + quad) * VGS + (ct * 16 + l15) * 8]);
      acc[ct] = __builtin_amdgcn_mfma_f32_16x16x32_bf16(pa, vb, acc[ct], 0, 0, 0);
    }
  }

  // S_w: reduce across the 16 col-lanes (l15), rows = quad*4+rr
#pragma unroll
  for (int rr = 0; rr < 4; ++rr) {
    float s = Sacc[rr];
    s += __shfl_xor(s, 1); s += __shfl_xor(s, 2);
    s += __shfl_xor(s, 4); s += __shfl_xor(s, 8);
    if (l15 == 0) Sw[((size_t)b * H + h) * W + wrow_base + r0 + rr] = s;
  }

  __syncthreads();  // done reading vbs; reuse as transpose buffer
  unsigned short* ob = vbs;  // [c][128] stride 132
#pragma unroll
  for (int ct = 0; ct < 4; ++ct) {
#pragma unroll
    for (int rr = 0; rr < 4; ++rr) {
      ob[(ct * 16 + l15) * 132 + wv * 16 + r0 + rr] = f2bf(acc[ct][rr]);
    }
  }
  __syncthreads();
  unsigned short* og = ow + (((size_t)b * H + h) * C) * W + w0;
  for (int idx = tid; idx < 64 * 64; idx += 512) {
    const int c = idx >> 6, wp = idx & 63;
    *(unsigned int*)(og + (size_t)c * W + 2 * wp) =
        *(const unsigned int*)(ob + c * 132 + 2 * wp);
  }
}

// ---------------------------------------------------------------------------
// K3: out_h unnormalized + S_h. Block=(third,w,b), 384 thr (6 waves), M=96
// rows of h (h0 in {0,96,174}; overlap rows recomputed identically).
// K-dim g padded to 288; g>=H and g==h masked to p=0 in epilogue.
// Outputs: oht [b][w][c][h] (bf16 unnormalized), Sh [b][h][w] (f32).
// ---------------------------------------------------------------------------
__global__ __launch_bounds__(384, 4)
void k_outh(const unsigned short* __restrict__ qhp,
            const unsigned short* __restrict__ khp,
            const unsigned short* __restrict__ vt,
            unsigned short* __restrict__ oht, float* __restrict__ Sh) {
  __shared__ __align__(16) unsigned short vbs[36 * VGS];  // 37440 B
  __shared__ __align__(16) unsigned short Pb[6 * 16 * PS];  // 7680 B
  const int bx = blockIdx.x, w = blockIdx.y, b = blockIdx.z;
  const int h0 = (bx == 0) ? 0 : (bx == 1) ? 96 : 174;
  const int tid = threadIdx.x;

  // stage V col (g-dim) swizzled; zeros for g >= H
  const unsigned short* vtb = vt + ((size_t)b * W + w) * H * C;
  for (int idx = tid; idx < 288 * 16; idx += 384) {
    const int g = idx >> 4, c4 = (idx & 15) * 4;
    ushort4 vv = make_ushort4(0, 0, 0, 0);
    if (g < H) vv = *(const ushort4*)(vtb + (size_t)g * C + c4);
    unsigned short* base = &vbs[(g >> 3) * VGS + c4 * 8 + (g & 7)];
    base[0]  = vv.x;
    base[8]  = vv.y;
    base[16] = vv.z;
    base[24] = vv.w;
  }

  const int lane = tid & 63, wv = tid >> 6;
  const int l15 = lane & 15, quad = lane >> 4;
  const int r0 = quad * 4;
  const int hrow_base = h0 + wv * 16;

  short8 qa = short8{0, 0, 0, 0, 0, 0, 0, 0};
  if (quad == 0)
    qa = *(const short8*)(qhp + (((size_t)b * W + w) * H + hrow_base + l15) * 8);
  const unsigned short* kCol = khp + (((size_t)b * W + w) * H) * 8;
  unsigned short* PbW = &Pb[wv * 16 * PS];

  f32x4 acc[4];
  float Sacc[4];
#pragma unroll
  for (int ct = 0; ct < 4; ++ct)
#pragma unroll
    for (int rr = 0; rr < 4; ++rr) acc[ct][rr] = 0.0f;
#pragma unroll
  for (int rr = 0; rr < 4; ++rr) Sacc[rr] = 0.0f;

  __syncthreads();

#pragma unroll
  for (int ci = 0; ci < 9; ++ci) {
    const int gc = ci * 32;
    f32x4 E[2];
#pragma unroll
    for (int nt = 0; nt < 2; ++nt) {
      short8 kb = short8{0, 0, 0, 0, 0, 0, 0, 0};
      if (quad == 0)
        kb = *(const short8*)(kCol + (size_t)(gc + nt * 16 + l15) * 8);
      E[nt] = __builtin_amdgcn_mfma_f32_16x16x32_bf16(
          qa, kb, f32x4{0.f, 0.f, 0.f, 0.f}, 0, 0, 0);
    }
#pragma unroll
    for (int nt = 0; nt < 2; ++nt) {
#pragma unroll
      for (int rr = 0; rr < 4; ++rr) {
        const int hrow = hrow_base + r0 + rr;
        const int g = gc + nt * 16 + l15;
        float p = 0.0f;
        if (g < H && g != hrow) {
          const float d = (float)(hrow - g);
          const float dw = __expf(d * d * (-INVH2));
          p = __expf(E[nt][rr] * dw);
        }
        Sacc[rr] += p;
        PbW[(r0 + rr) * PS + nt * 16 + l15] = f2bf(p);
      }
    }
    const short8 pa = *(const short8*)(&PbW[l15 * PS + quad * 8]);
#pragma unroll
    for (int ct = 0; ct < 4; ++ct) {
      const short8 vb =
          *(const short8*)(&vbs[(ci * 4 + quad) * VGS + (ct * 16 + l15) * 8]);
      acc[ct] = __builtin_amdgcn_mfma_f32_16x16x32_bf16(pa, vb, acc[ct], 0, 0, 0);
    }
  }

#pragma unroll
  for (int rr = 0; rr < 4; ++rr) {
    float s = Sacc[rr];
    s += __shfl_xor(s, 1); s += __shfl_xor(s, 2);
    s += __shfl_xor(s, 4); s += __shfl_xor(s, 8);
    if (l15 == 0) Sh[((size_t)b * H + hrow_base + r0 + rr) * W + w] = s;
  }

  __syncthreads();
  unsigned short* ob = vbs;  // [c][96] stride 100
#pragma unroll
  for (int ct = 0; ct < 4; ++ct) {
#pragma unroll
    for (int rr = 0; rr < 4; ++rr) {
      ob[(ct * 16 + l15) * 100 + wv * 16 + r0 + rr] = f2bf(acc[ct][rr]);
    }
  }
  __syncthreads();
  unsigned short* og = oht + (((size_t)b * W + w) * C) * H + h0;
  for (int idx = tid; idx < 64 * 48; idx += 384) {
    const int c = idx / 48, hp = idx - c * 48;
    *(unsigned int*)(og + (size_t)c * H + 2 * hp) =
        *(const unsigned int*)(ob + c * 100 + 2 * hp);
  }
}

// ---------------------------------------------------------------------------
// K4: out = gamma*(U_h + U_w)/(S_h+S_w) + x, LDS tile transpose for oht.
// ---------------------------------------------------------------------------
__global__ __launch_bounds__(256)
void k_combine(const unsigned short* __restrict__ oht,
               const unsigned short* __restrict__ ow,
               const float* __restrict__ Sh, const float* __restrict__ Sw,
               const float* __restrict__ x,
               const float* __restrict__ gp,
               float* __restrict__ out) {
  __shared__ float tile[32][33];
  const int b = blockIdx.z >> 6, c = blockIdx.z & 63;
  const int w0 = blockIdx.x * 32, h0 = blockIdx.y * 32;
  const int tx = threadIdx.x, ty = threadIdx.y;  // (32, 8)
#pragma unroll
  for (int i = 0; i < 4; ++i) {
    const int wl = ty + i * 8;
    const int hh = h0 + tx;
    float val = 0.0f;
    if (hh < H) val = bits2f(oht[(((size_t)b * W + (w0 + wl)) * C + c) * H + hh]);
    tile[wl][tx] = val;
  }
  __syncthreads();
  const float gamma = *gp;
#pragma unroll
  for (int i = 0; i < 4; ++i) {
    const int hl = ty + i * 8;
    const int hh = h0 + hl;
    if (hh < H) {
      const int ww = w0 + tx;
      const float uh = tile[tx][hl];
      const float uw = bits2f(ow[(((size_t)b * H + hh) * C + c) * W + ww]);
      const size_t si = ((size_t)b * H + hh) * W + ww;
      const float Z = Sh[si] + Sw[si];
      const float invZ = __builtin_amdgcn_rcpf(Z);
      const size_t xi = ((size_t)b * C + c) * HW + (size_t)hh * W + ww;
      out[xi] = fmaf(gamma * invZ, uh + uw, x[xi]);
    }
  }
}

}  // namespace

extern "C" void kernel_launch(void* const* d_in, const int* in_sizes, int n_in,
                              void* d_out, int out_size, void* d_ws, size_t ws_size,
                              hipStream_t stream) {
  (void)in_sizes; (void)n_in; (void)out_size; (void)ws_size;
  const float* x  = (const float*)d_in[0];
  const float* Wq = (const float*)d_in[1];
  const float* bq = (const float*)d_in[2];
  const float* Wk = (const float*)d_in[3];
  const float* bk = (const float*)d_in[4];
  const float* Wv = (const float*)d_in[5];
  const float* bv = (const float*)d_in[6];
  const float* gp = (const float*)d_in[7];
  float* out = (float*)d_out;

  char* p = (char*)d_ws;
  auto take = [&](size_t bytes) -> void* {
    char* r = p;
    p += (bytes + 255) & ~(size_t)255;
    return (void*)r;
  };
  unsigned short* qwp = (unsigned short*)take(sizeof(unsigned short) * (size_t)B * HW * 8);
  unsigned short* kwp = (unsigned short*)take(sizeof(unsigned short) * (size_t)B * HW * 8);
  unsigned short* qhp = (unsigned short*)take(sizeof(unsigned short) * (size_t)B * HW * 8);
  unsigned short* khp = (unsigned short*)take(sizeof(unsigned short) * (size_t)B * HW * 8);
  unsigned short* v   = (unsigned short*)take(sizeof(unsigned short) * (size_t)B * C * HW);
  unsigned short* vt  = (unsigned short*)take(sizeof(unsigned short) * (size_t)B * C * HW);
  unsigned short* oht = (unsigned short*)take(sizeof(unsigned short) * (size_t)B * C * HW);
  unsigned short* owb = (unsigned short*)take(sizeof(unsigned short) * (size_t)B * C * HW);
  float* Sh = (float*)take(sizeof(float) * (size_t)B * HW);
  float* Sw = (float*)take(sizeof(float) * (size_t)B * HW);

  hipLaunchKernelGGL(k_qkv, dim3((B * HW + 255) / 256), dim3(256), 0, stream,
                     x, Wq, bq, Wk, bk, Wv, bv, qwp, kwp, qhp, khp, v, vt);
  hipLaunchKernelGGL(k_outh, dim3(3, W, B), dim3(384), 0, stream,
                     qhp, khp, vt, oht, Sh);
  hipLaunchKernelGGL(k_outw, dim3(4, H, B), dim3(512), 0, stream,
                     qwp, kwp, v, owb, Sw);
  hipLaunchKernelGGL(k_combine, dim3(W / 32, (H + 31) / 32, B * C), dim3(32, 8), 0, stream,
                     oht, owb, Sh, Sw, x, gp, out);
}

// Round 4
// 483.440 us; speedup vs baseline: 4.1374x; 1.0269x over previous
//
#include <hip/hip_runtime.h>
#include <hip/hip_bf16.h>

namespace {

constexpr int B  = 2;
constexpr int C  = 64;
constexpr int CQ = 8;
constexpr int H  = 270;
constexpr int W  = 480;
constexpr int HW = H * W;
constexpr float INVH2 = 2.0f / (270.0f * 270.0f);  // dw_h = exp(-d^2 * INVH2)
constexpr float INVW2 = 2.0f / (480.0f * 480.0f);

typedef __attribute__((ext_vector_type(4))) float f32x4;
typedef __attribute__((ext_vector_type(8))) short short8;

__device__ __forceinline__ float bits2f(unsigned short u) {
  union { unsigned int i; float f; } cv;
  cv.i = ((unsigned int)u) << 16;
  return cv.f;
}

__device__ __forceinline__ unsigned short f2bf(float f) {
  union { __hip_bfloat16 b; unsigned short u; } cv;
  cv.b = __float2bfloat16(f);
  return cv.u;
}

__device__ __forceinline__ unsigned int pack2(float a, float b) {
  return ((unsigned int)f2bf(b) << 16) | (unsigned int)f2bf(a);
}

// ---------------------------------------------------------------------------
// K1: q/k/v 1x1 projections. One thread per pixel. Writes bf16 packs:
// qwp/kwp [b][h][w][8], qhp/khp [b][w][h][8], v [b][c][h][w], vt [b][w][h][c].
// ---------------------------------------------------------------------------
__global__ __launch_bounds__(256)
void k_qkv(const float* __restrict__ x,
           const float* __restrict__ Wq, const float* __restrict__ bq,
           const float* __restrict__ Wk, const float* __restrict__ bk,
           const float* __restrict__ Wv, const float* __restrict__ bv,
           unsigned short* __restrict__ qwp, unsigned short* __restrict__ kwp,
           unsigned short* __restrict__ qhp, unsigned short* __restrict__ khp,
           unsigned short* __restrict__ v, unsigned short* __restrict__ vt) {
  __shared__ __align__(16) float wql[CQ * C];
  __shared__ __align__(16) float wkl[CQ * C];
  __shared__ __align__(16) float wvl[C * C];
  __shared__ float bql[CQ], bkl[CQ], bvl[C];
  const int tid = threadIdx.x;
  for (int i = tid; i < CQ * C; i += 256) { wql[i] = Wq[i]; wkl[i] = Wk[i]; }
  for (int i = tid; i < C * C; i += 256) wvl[i] = Wv[i];
  if (tid < CQ) { bql[tid] = bq[tid]; bkl[tid] = bk[tid]; }
  if (tid < C) bvl[tid] = bv[tid];
  __syncthreads();
  const int pix = blockIdx.x * 256 + tid;
  if (pix >= B * HW) return;
  const int b = pix / HW;
  const int r = pix - b * HW;
  const int h = r / W;
  const int w = r - h * W;

  float qa[CQ], ka[CQ], va[C];
#pragma unroll
  for (int o = 0; o < CQ; ++o) { qa[o] = bql[o]; ka[o] = bkl[o]; }
#pragma unroll
  for (int o = 0; o < C; ++o) va[o] = bvl[o];

  const float* xp = x + (size_t)b * C * HW + r;
  for (int c = 0; c < C; c += 4) {
    const float x0 = xp[(size_t)(c + 0) * HW];
    const float x1 = xp[(size_t)(c + 1) * HW];
    const float x2 = xp[(size_t)(c + 2) * HW];
    const float x3 = xp[(size_t)(c + 3) * HW];
#pragma unroll
    for (int o = 0; o < CQ; ++o) {
      const float4 a = *(const float4*)(wql + o * C + c);
      qa[o] = fmaf(a.w, x3, fmaf(a.z, x2, fmaf(a.y, x1, fmaf(a.x, x0, qa[o]))));
      const float4 bb = *(const float4*)(wkl + o * C + c);
      ka[o] = fmaf(bb.w, x3, fmaf(bb.z, x2, fmaf(bb.y, x1, fmaf(bb.x, x0, ka[o]))));
    }
#pragma unroll
    for (int o = 0; o < C; ++o) {
      const float4 cc = *(const float4*)(wvl + o * C + c);
      va[o] = fmaf(cc.w, x3, fmaf(cc.z, x2, fmaf(cc.y, x1, fmaf(cc.x, x0, va[o]))));
    }
  }

  uint4 qp4, kp4;
  qp4.x = pack2(qa[0], qa[1]); qp4.y = pack2(qa[2], qa[3]);
  qp4.z = pack2(qa[4], qa[5]); qp4.w = pack2(qa[6], qa[7]);
  kp4.x = pack2(ka[0], ka[1]); kp4.y = pack2(ka[2], ka[3]);
  kp4.z = pack2(ka[4], ka[5]); kp4.w = pack2(ka[6], ka[7]);
  *(uint4*)(qwp + (size_t)pix * 8) = qp4;
  *(uint4*)(kwp + (size_t)pix * 8) = kp4;
  const size_t tbase = ((size_t)b * W + w) * H + h;
  *(uint4*)(qhp + tbase * 8) = qp4;
  *(uint4*)(khp + tbase * 8) = kp4;

  unsigned short* vp = v + (size_t)b * C * HW + r;
#pragma unroll
  for (int o = 0; o < C; ++o) vp[(size_t)o * HW] = f2bf(va[o]);
  unsigned short* vtp = vt + tbase * C;
#pragma unroll
  for (int j = 0; j < 16; ++j) {
    ushort4 u;
    u.x = f2bf(va[4 * j + 0]);
    u.y = f2bf(va[4 * j + 1]);
    u.z = f2bf(va[4 * j + 2]);
    u.w = f2bf(va[4 * j + 3]);
    *(ushort4*)(vtp + 4 * j) = u;
  }
}

constexpr int PS = 40;  // Pb row stride (bf16 elems); 80 B, 16B-aligned rows

// ---------------------------------------------------------------------------
// K2: out_w unnormalized + S_w. ONE block per (b,h): 960 thr = 15 waves,
// each wave owns 2 m-tiles of 16 w-rows (M=480). V row staged once to LDS
// [c][s] (stride 488). K/Q packs from global (L1-resident). Barrier-free
// K-loop: QK MFMA (K=8 in quad0, rest zero) -> exp epilogue (dw via LDS LUT)
// -> per-wave Pb -> PV MFMA. Outputs ow [b][h][c][w] bf16, Sw [b][h][w].
// ---------------------------------------------------------------------------
constexpr int VSW = 488;

__global__ __launch_bounds__(960, 4)
void k_outw(const unsigned short* __restrict__ qwp,
            const unsigned short* __restrict__ kwp,
            const unsigned short* __restrict__ v,
            unsigned short* __restrict__ ow, float* __restrict__ Sw) {
  __shared__ __align__(16) unsigned short smem[52352];  // 104704 B
  unsigned short* vbs = smem;             // 64*488 = 31232 elems
  unsigned short* Pb  = smem + 31232;     // 15*32*40 = 19200 elems
  float* dwt = (float*)(smem + 31232 + 19200);  // 960 f32
  const int h = blockIdx.x, b = blockIdx.y;
  const int tid = threadIdx.x;

  const unsigned short* vrow = v + (size_t)b * C * HW + (size_t)h * W;
  for (int idx = tid; idx < 64 * 120; idx += 960) {
    const int c = idx / 120, s4 = (idx - c * 120) * 4;
    *(ushort4*)(vbs + c * VSW + s4) = *(const ushort4*)(vrow + (size_t)c * HW + s4);
  }
  {
    const float d = (float)(tid - 479);
    dwt[tid] = __expf(-(d * d) * INVW2);
  }

  const int lane = tid & 63, wv = tid >> 6;
  const int l15 = lane & 15, quad = lane >> 4, r0 = quad * 4;
  const int m0 = wv * 32;
  unsigned short* PbW = Pb + wv * 32 * PS;
  const size_t rowbase = ((size_t)b * H + h) * W;

  short8 qa0 = short8{0, 0, 0, 0, 0, 0, 0, 0};
  short8 qa1 = short8{0, 0, 0, 0, 0, 0, 0, 0};
  if (quad == 0) {
    qa0 = *(const short8*)(qwp + (rowbase + m0 + l15) * 8);
    qa1 = *(const short8*)(qwp + (rowbase + m0 + 16 + l15) * 8);
  }
  const unsigned short* kRow = kwp + rowbase * 8;

  f32x4 acc[2][4];
  float Sacc[2][4];
#pragma unroll
  for (int mt = 0; mt < 2; ++mt)
#pragma unroll
    for (int ct = 0; ct < 4; ++ct)
#pragma unroll
      for (int rr = 0; rr < 4; ++rr) acc[mt][ct][rr] = 0.0f;
#pragma unroll
  for (int mt = 0; mt < 2; ++mt)
#pragma unroll
    for (int rr = 0; rr < 4; ++rr) Sacc[mt][rr] = 0.0f;

  __syncthreads();

  for (int ci = 0; ci < 15; ++ci) {
    const int sc = ci * 32;
    const short8 kb0 = *(const short8*)(kRow + (size_t)(sc + l15) * 8);
    const short8 kb1 = *(const short8*)(kRow + (size_t)(sc + 16 + l15) * 8);
    const f32x4 z4 = f32x4{0.f, 0.f, 0.f, 0.f};
#pragma unroll
    for (int mt = 0; mt < 2; ++mt) {
      const short8 qa = mt ? qa1 : qa0;
      const f32x4 E0 = __builtin_amdgcn_mfma_f32_16x16x32_bf16(qa, kb0, z4, 0, 0, 0);
      const f32x4 E1 = __builtin_amdgcn_mfma_f32_16x16x32_bf16(qa, kb1, z4, 0, 0, 0);
      const int mrow = m0 + mt * 16 + r0;
#pragma unroll
      for (int rr = 0; rr < 4; ++rr) {
        const int m = mrow + rr;
        const float p0 = __expf(E0[rr] * dwt[m - (sc + l15) + 479]);
        const float p1 = __expf(E1[rr] * dwt[m - (sc + 16 + l15) + 479]);
        Sacc[mt][rr] += p0 + p1;
        PbW[(mt * 16 + r0 + rr) * PS + l15] = f2bf(p0);
        PbW[(mt * 16 + r0 + rr) * PS + 16 + l15] = f2bf(p1);
      }
    }
    const short8 pa0 = *(const short8*)(PbW + (l15) * PS + quad * 8);
    const short8 pa1 = *(const short8*)(PbW + (16 + l15) * PS + quad * 8);
#pragma unroll
    for (int ct = 0; ct < 4; ++ct) {
      const short8 vb = *(const short8*)(vbs + (ct * 16 + l15) * VSW + sc + quad * 8);
      acc[0][ct] = __builtin_amdgcn_mfma_f32_16x16x32_bf16(pa0, vb, acc[0][ct], 0, 0, 0);
      acc[1][ct] = __builtin_amdgcn_mfma_f32_16x16x32_bf16(pa1, vb, acc[1][ct], 0, 0, 0);
    }
  }

#pragma unroll
  for (int mt = 0; mt < 2; ++mt)
#pragma unroll
    for (int rr = 0; rr < 4; ++rr) {
      float s = Sacc[mt][rr];
      s += __shfl_xor(s, 1); s += __shfl_xor(s, 2);
      s += __shfl_xor(s, 4); s += __shfl_xor(s, 8);
      if (l15 == 0) Sw[rowbase + m0 + mt * 16 + r0 + rr] = s;
    }

  __syncthreads();  // vbs reads done; reuse as [c][480] transpose buffer
  unsigned short* ob = vbs;
#pragma unroll
  for (int mt = 0; mt < 2; ++mt)
#pragma unroll
    for (int ct = 0; ct < 4; ++ct)
#pragma unroll
      for (int rr = 0; rr < 4; ++rr)
        ob[(ct * 16 + l15) * VSW + m0 + mt * 16 + r0 + rr] = f2bf(acc[mt][ct][rr]);
  __syncthreads();
  unsigned short* og = ow + ((size_t)b * H + h) * C * W;
  for (int idx = tid; idx < 64 * 240; idx += 960) {
    const int c = idx / 240, wp = idx - c * 240;
    *(unsigned int*)(og + (size_t)c * W + 2 * wp) =
        *(const unsigned int*)(ob + c * VSW + 2 * wp);
  }
}

// ---------------------------------------------------------------------------
// K3: out_h unnormalized + S_h. ONE block per (b,w): 576 thr = 9 waves,
// each wave 2 m-tiles (M=288, rows >= 270 are pad: loads clamped, p masked).
// V col staged once to LDS [c][g] (stride 296). Outputs oht [b][w][c][h],
// Sh [b][h][w].
// ---------------------------------------------------------------------------
constexpr int VSH = 296;

__global__ __launch_bounds__(576, 5)
void k_outh(const unsigned short* __restrict__ qhp,
            const unsigned short* __restrict__ khp,
            const unsigned short* __restrict__ vt,
            unsigned short* __restrict__ oht, float* __restrict__ Sh) {
  __shared__ __align__(16) unsigned short smem[31616];  // 63232 B
  unsigned short* vbs = smem;             // 64*296 = 18944 elems
  unsigned short* Pb  = smem + 18944;     // 9*32*40 = 11520 elems
  float* dwt = (float*)(smem + 18944 + 11520);  // 576 f32
  const int w = blockIdx.x, b = blockIdx.y;
  const int tid = threadIdx.x;

  const unsigned short* vtb = vt + ((size_t)b * W + w) * H * C;
  for (int idx = tid; idx < 288 * 16; idx += 576) {
    const int g = idx >> 4, c4 = (idx & 15) * 4;
    ushort4 vv = make_ushort4(0, 0, 0, 0);
    if (g < H) vv = *(const ushort4*)(vtb + (size_t)g * C + c4);
    vbs[(c4 + 0) * VSH + g] = vv.x;
    vbs[(c4 + 1) * VSH + g] = vv.y;
    vbs[(c4 + 2) * VSH + g] = vv.z;
    vbs[(c4 + 3) * VSH + g] = vv.w;
  }
  {
    const float d = (float)(tid - 287);
    dwt[tid] = __expf(-(d * d) * INVH2);
  }

  const int lane = tid & 63, wv = tid >> 6;
  const int l15 = lane & 15, quad = lane >> 4, r0 = quad * 4;
  const int m0 = wv * 32;
  unsigned short* PbW = Pb + wv * 32 * PS;
  const size_t colbase = ((size_t)b * W + w) * H;

  short8 qa0 = short8{0, 0, 0, 0, 0, 0, 0, 0};
  short8 qa1 = short8{0, 0, 0, 0, 0, 0, 0, 0};
  if (quad == 0) {
    qa0 = *(const short8*)(qhp + (colbase + min(m0 + l15, H - 1)) * 8);
    qa1 = *(const short8*)(qhp + (colbase + min(m0 + 16 + l15, H - 1)) * 8);
  }
  const unsigned short* kCol = khp + colbase * 8;

  f32x4 acc[2][4];
  float Sacc[2][4];
#pragma unroll
  for (int mt = 0; mt < 2; ++mt)
#pragma unroll
    for (int ct = 0; ct < 4; ++ct)
#pragma unroll
      for (int rr = 0; rr < 4; ++rr) acc[mt][ct][rr] = 0.0f;
#pragma unroll
  for (int mt = 0; mt < 2; ++mt)
#pragma unroll
    for (int rr = 0; rr < 4; ++rr) Sacc[mt][rr] = 0.0f;

  __syncthreads();

  for (int ci = 0; ci < 9; ++ci) {
    const int gc = ci * 32;
    const int g0 = gc + l15, g1 = gc + 16 + l15;
    const short8 kb0 = *(const short8*)(kCol + (size_t)min(g0, H - 1) * 8);
    const short8 kb1 = *(const short8*)(kCol + (size_t)min(g1, H - 1) * 8);
    const f32x4 z4 = f32x4{0.f, 0.f, 0.f, 0.f};
#pragma unroll
    for (int mt = 0; mt < 2; ++mt) {
      const short8 qa = mt ? qa1 : qa0;
      const f32x4 E0 = __builtin_amdgcn_mfma_f32_16x16x32_bf16(qa, kb0, z4, 0, 0, 0);
      const f32x4 E1 = __builtin_amdgcn_mfma_f32_16x16x32_bf16(qa, kb1, z4, 0, 0, 0);
      const int mrow = m0 + mt * 16 + r0;
#pragma unroll
      for (int rr = 0; rr < 4; ++rr) {
        const int m = mrow + rr;
        float p0 = 0.0f, p1 = 0.0f;
        if (g0 < H && g0 != m) p0 = __expf(E0[rr] * dwt[m - g0 + 287]);
        if (g1 < H && g1 != m) p1 = __expf(E1[rr] * dwt[m - g1 + 287]);
        Sacc[mt][rr] += p0 + p1;
        PbW[(mt * 16 + r0 + rr) * PS + l15] = f2bf(p0);
        PbW[(mt * 16 + r0 + rr) * PS + 16 + l15] = f2bf(p1);
      }
    }
    const short8 pa0 = *(const short8*)(PbW + (l15) * PS + quad * 8);
    const short8 pa1 = *(const short8*)(PbW + (16 + l15) * PS + quad * 8);
#pragma unroll
    for (int ct = 0; ct < 4; ++ct) {
      const short8 vb = *(const short8*)(vbs + (ct * 16 + l15) * VSH + gc + quad * 8);
      acc[0][ct] = __builtin_amdgcn_mfma_f32_16x16x32_bf16(pa0, vb, acc[0][ct], 0, 0, 0);
      acc[1][ct] = __builtin_amdgcn_mfma_f32_16x16x32_bf16(pa1, vb, acc[1][ct], 0, 0, 0);
    }
  }

#pragma unroll
  for (int mt = 0; mt < 2; ++mt)
#pragma unroll
    for (int rr = 0; rr < 4; ++rr) {
      float s = Sacc[mt][rr];
      s += __shfl_xor(s, 1); s += __shfl_xor(s, 2);
      s += __shfl_xor(s, 4); s += __shfl_xor(s, 8);
      const int m = m0 + mt * 16 + r0 + rr;
      if (l15 == 0 && m < H) Sh[((size_t)b * H + m) * W + w] = s;
    }

  __syncthreads();
  unsigned short* ob = vbs;  // [c][288] stride 296
#pragma unroll
  for (int mt = 0; mt < 2; ++mt)
#pragma unroll
    for (int ct = 0; ct < 4; ++ct)
#pragma unroll
      for (int rr = 0; rr < 4; ++rr)
        ob[(ct * 16 + l15) * VSH + m0 + mt * 16 + r0 + rr] = f2bf(acc[mt][ct][rr]);
  __syncthreads();
  unsigned short* og = oht + ((size_t)b * W + w) * C * H;
  for (int idx = tid; idx < 64 * 135; idx += 576) {
    const int c = idx / 135, hp = idx - c * 135;
    *(unsigned int*)(og + (size_t)c * H + 2 * hp) =
        *(const unsigned int*)(ob + c * VSH + 2 * hp);
  }
}

// ---------------------------------------------------------------------------
// K4: out = gamma*(U_h + U_w)/(S_h+S_w) + x, LDS tile transpose for oht.
// ---------------------------------------------------------------------------
__global__ __launch_bounds__(256)
void k_combine(const unsigned short* __restrict__ oht,
               const unsigned short* __restrict__ ow,
               const float* __restrict__ Sh, const float* __restrict__ Sw,
               const float* __restrict__ x,
               const float* __restrict__ gp,
               float* __restrict__ out) {
  __shared__ float tile[32][33];
  const int b = blockIdx.z >> 6, c = blockIdx.z & 63;
  const int w0 = blockIdx.x * 32, h0 = blockIdx.y * 32;
  const int tx = threadIdx.x, ty = threadIdx.y;  // (32, 8)
#pragma unroll
  for (int i = 0; i < 4; ++i) {
    const int wl = ty + i * 8;
    const int hh = h0 + tx;
    float val = 0.0f;
    if (hh < H) val = bits2f(oht[(((size_t)b * W + (w0 + wl)) * C + c) * H + hh]);
    tile[wl][tx] = val;
  }
  __syncthreads();
  const float gamma = *gp;
#pragma unroll
  for (int i = 0; i < 4; ++i) {
    const int hl = ty + i * 8;
    const int hh = h0 + hl;
    if (hh < H) {
      const int ww = w0 + tx;
      const float uh = tile[tx][hl];
      const float uw = bits2f(ow[(((size_t)b * H + hh) * C + c) * W + ww]);
      const size_t si = ((size_t)b * H + hh) * W + ww;
      const float Z = Sh[si] + Sw[si];
      const float invZ = __builtin_amdgcn_rcpf(Z);
      const size_t xi = ((size_t)b * C + c) * HW + (size_t)hh * W + ww;
      out[xi] = fmaf(gamma * invZ, uh + uw, x[xi]);
    }
  }
}

}  // namespace

extern "C" void kernel_launch(void* const* d_in, const int* in_sizes, int n_in,
                              void* d_out, int out_size, void* d_ws, size_t ws_size,
                              hipStream_t stream) {
  (void)in_sizes; (void)n_in; (void)out_size; (void)ws_size;
  const float* x  = (const float*)d_in[0];
  const float* Wq = (const float*)d_in[1];
  const float* bq = (const float*)d_in[2];
  const float* Wk = (const float*)d_in[3];
  const float* bk = (const float*)d_in[4];
  const float* Wv = (const float*)d_in[5];
  const float* bv = (const float*)d_in[6];
  const float* gp = (const float*)d_in[7];
  float* out = (float*)d_out;

  char* p = (char*)d_ws;
  auto take = [&](size_t bytes) -> void* {
    char* r = p;
    p += (bytes + 255) & ~(size_t)255;
    return (void*)r;
  };
  unsigned short* qwp = (unsigned short*)take(sizeof(unsigned short) * (size_t)B * HW * 8);
  unsigned short* kwp = (unsigned short*)take(sizeof(unsigned short) * (size_t)B * HW * 8);
  unsigned short* qhp = (unsigned short*)take(sizeof(unsigned short) * (size_t)B * HW * 8);
  unsigned short* khp = (unsigned short*)take(sizeof(unsigned short) * (size_t)B * HW * 8);
  unsigned short* v   = (unsigned short*)take(sizeof(unsigned short) * (size_t)B * C * HW);
  unsigned short* vt  = (unsigned short*)take(sizeof(unsigned short) * (size_t)B * C * HW);
  unsigned short* oht = (unsigned short*)take(sizeof(unsigned short) * (size_t)B * C * HW);
  unsigned short* owb = (unsigned short*)take(sizeof(unsigned short) * (size_t)B * C * HW);
  float* Sh = (float*)take(sizeof(float) * (size_t)B * HW);
  float* Sw = (float*)take(sizeof(float) * (size_t)B * HW);

  hipLaunchKernelGGL(k_qkv, dim3((B * HW + 255) / 256), dim3(256), 0, stream,
                     x, Wq, bq, Wk, bk, Wv, bv, qwp, kwp, qhp, khp, v, vt);
  hipLaunchKernelGGL(k_outh, dim3(W, B), dim3(576), 0, stream,
                     qhp, khp, vt, oht, Sh);
  hipLaunchKernelGGL(k_outw, dim3(H, B), dim3(960), 0, stream,
                     qwp, kwp, v, owb, Sw);
  hipLaunchKernelGGL(k_combine, dim3(W / 32, (H + 31) / 32, B * C), dim3(32, 8), 0, stream,
                     oht, owb, Sh, Sw, x, gp, out);
}